// Round 2
// baseline (13264.348 us; speedup 1.0000x reference)
//
#include <hip/hip_runtime.h>
#include <hip/hip_bf16.h>
#include <math.h>

#define B_ 64
#define T_ 104
#define FEAT_ 20
#define PEMB_ 64
#define COND_ 256
#define SUB_ 40
#define NBF_ 100
#define STEPS_ 400

typedef short short8 __attribute__((ext_vector_type(8)));
typedef float floatx4 __attribute__((ext_vector_type(4)));

__device__ inline unsigned short f2bf(float x){
  unsigned int u = __float_as_uint(x);
  unsigned int r = (u + 0x7fffu + ((u >> 16) & 1u)) >> 16;
  return (unsigned short)r;
}
__device__ inline float fast_tanh(float x){
  float e = __expf(2.f*x);
  return 1.f - 2.f*__builtin_amdgcn_rcpf(e + 1.f);
}
__device__ inline float fast_sigm(float x){
  return __builtin_amdgcn_rcpf(1.f + __expf(-x));
}
__device__ inline floatx4 mfma16(short8 a, short8 b, floatx4 c){
  return __builtin_amdgcn_mfma_f32_16x16x32_bf16(a, b, c, 0, 0, 0);
}
__device__ inline void fence_acq(){ __builtin_amdgcn_fence(__ATOMIC_ACQUIRE, "agent"); }
__device__ inline void fence_rel(){ __builtin_amdgcn_fence(__ATOMIC_RELEASE, "agent"); }

// ---------------- phase embedding ----------------
__global__ void k_phase(const int* __restrict__ period, const float* __restrict__ rshift,
                        float* __restrict__ pr, float* __restrict__ pi){
  int b = blockIdx.x;
  __shared__ float cumf[NBF_], w0f[NBF_];
  if (threadIdx.x == 0){
    double acc = 2.0*M_PI*(double)rshift[b];
    for (int f = 0; f < NBF_; ++f){
      double w0 = 2.0*M_PI/(double)period[b*T_ + 3 + f];
      cumf[f] = (float)fmod(acc, 2.0*M_PI);
      w0f[f] = (float)w0;
      acc += 160.0*w0;
    }
  }
  __syncthreads();
  for (int e = threadIdx.x; e < NBF_*160; e += blockDim.x){
    int f = e/160, j = e - f*160;
    float ph = cumf[f] + w0f[f]*(float)j;
    int s = f*4 + j/40, u = j%40;
    pr[((size_t)b*STEPS_ + s)*SUB_ + u] = cosf(ph);
    pi[((size_t)b*STEPS_ + s)*SUB_ + u] = sinf(ph);
  }
}

// ---------------- prep: zero counters/buffers, transpose conv weights ----------------
__global__ void k_prep(const float* __restrict__ c1w, const float* __restrict__ c2w,
                       float* __restrict__ w1t, float* __restrict__ w2t,
                       unsigned int* __restrict__ ctr, unsigned int* __restrict__ bufs){
  size_t tid = (size_t)blockIdx.x*blockDim.x + threadIdx.x;
  size_t nt = (size_t)gridDim.x*blockDim.x;
  for (size_t e = tid; e < 16; e += nt) ctr[e] = 0u;
  for (size_t e = tid; e < 65536; e += nt) bufs[e] = 0u;   // tt2/h1/h2/h3 (4 x 64KiB bytes)
  for (size_t e = tid; e < 768u*256u; e += nt){
    int kk = (int)(e >> 8), o = (int)(e & 255);
    int i = kk & 255, kc = kk >> 8;
    w1t[e] = c1w[(size_t)o*768 + i*3 + kc];
    w2t[e] = c2w[(size_t)o*768 + i*3 + kc];
  }
}

// ---------------- generic fp32 tiled GEMM (M x K x 256), per-mode A/B gather ----------------
// MODE 0: fd1   A=[features|pembed[period]] K=84->96   C=tanh(+fd1_b)
// MODE 1: conv1 A=sliding windows of t_buf  K=768      C=tanh(+conv1_b)
// MODE 2: conv2 A=sliding windows of x1     K=768      C=tanh(+conv2_b)
// MODE 3: fd2   A=x2                        K=256      C=tanh(+fd2_b)
// MODE 4: tt1p  A=[c(rep4)|pr|pi]           K=336      C=acc+sd1_b (no tanh)
template<int MODE>
__global__ __launch_bounds__(256) void k_gemm(
    const float* __restrict__ a0, const float* __restrict__ a1, const float* __restrict__ a2,
    const int* __restrict__ ip,
    const float* __restrict__ Bm, const float* __restrict__ bias, float* __restrict__ C)
{
  constexpr int KT = (MODE==0) ? 6 : (MODE==1||MODE==2) ? 48 : (MODE==3) ? 16 : 21;
  __shared__ float As[16][68];
  __shared__ float Bs[16][68];
  int tid = threadIdx.x;
  int m0 = blockIdx.x*64, n0 = blockIdx.y*64;
  int tx = tid & 15, ty = tid >> 4;
  float acc[4][4] = {};
  int am = m0 + (tid >> 2);
  int akq = (tid & 3)*4;
  int bk = tid >> 4;
  int bn4 = (tid & 15)*4;

  for (int kt = 0; kt < KT; ++kt){
    int kbase = kt*16;
    // ---- A tile ----
    float av[4];
    {
      int k0 = kbase + akq;
      if constexpr (MODE==0){
        if (k0 < 20){
          const float* p = a0 + (size_t)am*FEAT_ + k0;
          #pragma unroll
          for (int u=0;u<4;++u) av[u] = p[u];
        } else if (k0 < 84){
          const float* p = a1 + (size_t)ip[am]*PEMB_ + (k0-20);
          #pragma unroll
          for (int u=0;u<4;++u) av[u] = p[u];
        } else { av[0]=av[1]=av[2]=av[3]=0.f; }
      } else if constexpr (MODE==1){
        int b = am/102, t2 = am - b*102;
        int i = k0 & 255, kc = k0 >> 8;
        const float* p = a0 + ((size_t)(b*T_ + t2 + kc))*COND_ + i;
        #pragma unroll
        for (int u=0;u<4;++u) av[u] = p[u];
      } else if constexpr (MODE==2){
        int b = am/100, t2 = am - b*100;
        int i = k0 & 255, kc = k0 >> 8;
        const float* p = a0 + ((size_t)(b*102 + t2 + kc))*COND_ + i;
        #pragma unroll
        for (int u=0;u<4;++u) av[u] = p[u];
      } else if constexpr (MODE==3){
        const float* p = a0 + (size_t)am*COND_ + k0;
        #pragma unroll
        for (int u=0;u<4;++u) av[u] = p[u];
      } else {
        int b = am/400, s = am - b*400;
        const float* p;
        if (k0 < 256)      p = a0 + ((size_t)(b*100 + (s>>2)))*COND_ + k0;
        else if (k0 < 296) p = a1 + ((size_t)(b*400 + s))*SUB_ + (k0-256);
        else               p = a2 + ((size_t)(b*400 + s))*SUB_ + (k0-296);
        #pragma unroll
        for (int u=0;u<4;++u) av[u] = p[u];
      }
    }
    // ---- B tile ----
    float bv[4];
    {
      int kB = kbase + bk;
      if constexpr (MODE==0){
        if (kB < 84){
          const float* p = Bm + (size_t)kB*256 + n0 + bn4;
          #pragma unroll
          for (int u=0;u<4;++u) bv[u] = p[u];
        } else { bv[0]=bv[1]=bv[2]=bv[3]=0.f; }
      } else if constexpr (MODE==4){
        int krow = (kB < 256) ? kB : kB + 40;
        const float* p = Bm + (size_t)krow*256 + n0 + bn4;
        #pragma unroll
        for (int u=0;u<4;++u) bv[u] = p[u];
      } else {
        const float* p = Bm + (size_t)kB*256 + n0 + bn4;
        #pragma unroll
        for (int u=0;u<4;++u) bv[u] = p[u];
      }
    }
    #pragma unroll
    for (int u=0;u<4;++u) As[akq+u][tid>>2] = av[u];
    #pragma unroll
    for (int u=0;u<4;++u) Bs[bk][bn4+u] = bv[u];
    __syncthreads();
    #pragma unroll
    for (int k = 0; k < 16; ++k){
      float a4[4], b4[4];
      #pragma unroll
      for (int i=0;i<4;++i) a4[i] = As[k][ty*4+i];
      #pragma unroll
      for (int j=0;j<4;++j) b4[j] = Bs[k][tx*4+j];
      #pragma unroll
      for (int i=0;i<4;++i)
        #pragma unroll
        for (int j=0;j<4;++j)
          acc[i][j] += a4[i]*b4[j];
    }
    __syncthreads();
  }
  #pragma unroll
  for (int i=0;i<4;++i){
    int m = m0 + ty*4 + i;
    #pragma unroll
    for (int j=0;j<4;++j){
      int n = n0 + tx*4 + j;
      float v = acc[i][j] + bias[n];
      if constexpr (MODE != 4) v = fast_tanh(v);
      C[(size_t)m*256 + n] = v;
    }
  }
}

// ---------------- persistent AR scan ----------------
// grid 256 = 4 clusters x (16 S1 + 16 G1 + 16 G2 + 16 G3), 256 thr/block, MFMA bf16.
__global__ __launch_bounds__(256, 1) void k_scan(
  const float* __restrict__ sd1_w, const float* __restrict__ sd2_w, const float* __restrict__ sd2_b,
  const float* __restrict__ g1_wi, const float* __restrict__ g1_bi, const float* __restrict__ g1_wh, const float* __restrict__ g1_bh,
  const float* __restrict__ g2_wi, const float* __restrict__ g2_bi, const float* __restrict__ g2_wh, const float* __restrict__ g2_bh,
  const float* __restrict__ g3_wi, const float* __restrict__ g3_bi, const float* __restrict__ g3_wh, const float* __restrict__ g3_bh,
  const float* __restrict__ out_w, const float* __restrict__ out_b,
  const float* __restrict__ tt1p,
  unsigned short* __restrict__ tt2buf, unsigned short* __restrict__ h1buf,
  unsigned short* __restrict__ h2buf, unsigned short* __restrict__ h3buf,
  unsigned int* __restrict__ ctr, float* __restrict__ out)
{
  __shared__ __align__(16) char smem[65536];
  int tid = threadIdx.x;
  int lane = tid & 63, wave = tid >> 6;
  int q = lane >> 4, nI = lane & 15;
  int bI = blockIdx.x;
  int g = bI >> 6, rr = bI & 63;
  int set = rr >> 4, sl = rr & 15;
  int b0 = g*16;
  unsigned int* myctr = ctr + g*4;

  if (set == 0){
    // ===== S1: h3 -> prev -> tt1 -> tt2-slice =====
    char* outwF = smem;            // 24576: out_w frags (3 ntiles x 8 ktiles)
    char* sd1p0 = smem + 24576;    // 16384: sd1 prev-rows, K-tile0 (k 0..31)
    char* sd1p1 = smem + 40960;    // 4096:  sd1 prev-rows, K-tile1 (k 32..39, q==0 lanes)
    char* sd2F  = smem + 45056;    // 8192:  sd2 slice frags (8 ktiles)
    char* stage = smem + 53248;    // 8192:  16 rows x 32 swizzled 16B chunks
    char* prevl = smem + 61440;    // 2304:  16 x 72 bf16
    int col1 = sl*16 + nI;

    for (int t = wave; t < 24; t += 4){
      int nt = t >> 3, kk = t & 7;
      int c = nt*16 + nI;
      unsigned short v[8];
      #pragma unroll
      for (int j = 0; j < 8; ++j){
        int k = kk*32 + q*8 + j;
        v[j] = (c < 40) ? f2bf(out_w[(size_t)k*40 + c]) : (unsigned short)0;
      }
      *(short8*)(outwF + (t*64 + lane)*16) = *(short8*)v;
    }
    for (int t = wave; t < 16; t += 4){
      unsigned short v[8];
      #pragma unroll
      for (int j = 0; j < 8; ++j){
        int k = q*8 + j;
        v[j] = f2bf(sd1_w[(size_t)(256+k)*256 + t*16 + nI]);
      }
      *(short8*)(sd1p0 + (t*64 + lane)*16) = *(short8*)v;
    }
    {
      int nt = tid >> 4, ln = tid & 15;
      unsigned short v[8];
      #pragma unroll
      for (int j = 0; j < 8; ++j)
        v[j] = f2bf(sd1_w[(size_t)(256+32+j)*256 + nt*16 + ln]);
      *(short8*)(sd1p1 + tid*16) = *(short8*)v;
    }
    for (int t = wave; t < 8; t += 4){
      unsigned short v[8];
      #pragma unroll
      for (int j = 0; j < 8; ++j){
        int k = t*32 + q*8 + j;
        v[j] = f2bf(sd2_w[(size_t)k*256 + col1]);
      }
      *(short8*)(sd2F + (t*64 + lane)*16) = *(short8*)v;
    }
    for (int e = tid; e < 16*72; e += 256) *(unsigned short*)(prevl + e*2) = 0;
    float bout = 0.f;
    if (wave < 3){ int c = wave*16 + nI; if (c < 40) bout = out_b[c]; }
    float bsd2 = sd2_b[col1];
    __syncthreads();

    for (int s = 0; s <= STEPS_; ++s){
      if (s > 0){
        if (tid == 0){
          unsigned int tgt = 16u*(unsigned)s;
          while (__hip_atomic_load(myctr+3, __ATOMIC_RELAXED, __HIP_MEMORY_SCOPE_AGENT) < tgt)
            __builtin_amdgcn_s_sleep(1);
        }
        __syncthreads();
        fence_acq();
        const unsigned short* h3s = h3buf + ((size_t)((s+1)&1)*4 + g)*4096;
        for (int c = tid; c < 512; c += 256){
          int row = c >> 5, gc = c & 31;
          int4 v = *(const int4*)(h3s + row*256 + gc*8);
          *(int4*)(stage + (row*32 + (gc ^ (row & 7)))*16) = v;
        }
        __syncthreads();
        if (wave < 3){
          floatx4 acc = {0.f,0.f,0.f,0.f};
          #pragma unroll
          for (int kk = 0; kk < 8; ++kk){
            short8 a = *(const short8*)(stage + (nI*32 + ((kk*4+q) ^ (nI & 7)))*16);
            short8 b = *(const short8*)(outwF + ((wave*8+kk)*64 + lane)*16);
            acc = mfma16(a, b, acc);
          }
          int c = wave*16 + nI;
          #pragma unroll
          for (int i = 0; i < 4; ++i){
            int row = q*4 + i;
            float pv = (c < 40) ? fast_tanh(acc[i] + bout) : 0.f;
            *(unsigned short*)(prevl + (row*72 + c)*2) = f2bf(pv);
            if (sl == 0 && c < 40)
              out[(size_t)(b0+row)*16000 + (size_t)(s-1)*40 + c] = pv;
          }
        }
      }
      if (s == STEPS_) break;
      __syncthreads();
      // tt1 = tanh(tt1p[s] + prev @ sd1p) -> stage (full 16x256, replicated)
      #pragma unroll
      for (int ii = 0; ii < 4; ++ii){
        int nt = wave*4 + ii;
        floatx4 acc = {0.f,0.f,0.f,0.f};
        short8 a0v = *(const short8*)(prevl + nI*144 + q*16);
        short8 b0v = *(const short8*)(sd1p0 + (nt*64 + lane)*16);
        acc = mfma16(a0v, b0v, acc);
        short8 a1v = *(const short8*)(prevl + nI*144 + 64 + q*16);
        short8 b1v = {0,0,0,0,0,0,0,0};
        if (q == 0) b1v = *(const short8*)(sd1p1 + (nt*16 + nI)*16);
        acc = mfma16(a1v, b1v, acc);
        int c = nt*16 + nI;
        #pragma unroll
        for (int i = 0; i < 4; ++i){
          int row = q*4 + i;
          float tv = fast_tanh(acc[i] + tt1p[((size_t)(b0+row)*STEPS_ + s)*COND_ + c]);
          int gc = c >> 3;
          *(unsigned short*)(stage + (row*32 + (gc ^ (row & 7)))*16 + (c & 7)*2) = f2bf(tv);
        }
      }
      __syncthreads();
      if (wave == 0){
        floatx4 acc = {0.f,0.f,0.f,0.f};
        #pragma unroll
        for (int kk = 0; kk < 8; ++kk){
          short8 a = *(const short8*)(stage + (nI*32 + ((kk*4+q) ^ (nI & 7)))*16);
          short8 b = *(const short8*)(sd2F + (kk*64 + lane)*16);
          acc = mfma16(a, b, acc);
        }
        unsigned short* t2 = tt2buf + ((size_t)(s&1)*4 + g)*4096;
        #pragma unroll
        for (int i = 0; i < 4; ++i){
          int row = q*4 + i;
          t2[row*256 + col1] = f2bf(fast_tanh(acc[i] + bsd2));
        }
      }
      __syncthreads();
      if (tid == 0){
        fence_rel();
        __hip_atomic_fetch_add(myctr+0, 1u, __ATOMIC_RELAXED, __HIP_MEMORY_SCOPE_AGENT);
      }
    }
  } else {
    // ===== GRU set (set-1 = GRU index) =====
    int gi_ = set - 1;
    const float* wi = (gi_==0) ? g1_wi : (gi_==1) ? g2_wi : g3_wi;
    const float* wh = (gi_==0) ? g1_wh : (gi_==1) ? g2_wh : g3_wh;
    const float* bi = (gi_==0) ? g1_bi : (gi_==1) ? g2_bi : g3_bi;
    const float* bh = (gi_==0) ? g1_bh : (gi_==1) ? g2_bh : g3_bh;
    unsigned short* hOut = (gi_==0) ? h1buf : (gi_==1) ? h2buf : h3buf;
    const unsigned short* xBase = (gi_==0) ? tt2buf : (gi_==1) ? h1buf : h2buf;
    char* wlds  = smem;          // 49152: tiles 0..15 r, 16..31 z, 32..39 i_n, 40..47 h_n
    char* stage = smem + 49152;  // 16384: 16 rows x 64 swizzled 16B chunks ([x|h])
    int hc0 = sl*16;

    for (int t = wave; t < 48; t += 4){
      unsigned short v[8];
      #pragma unroll
      for (int j = 0; j < 8; ++j){
        float w;
        if (t < 32){
          int k512 = (t & 15)*32 + q*8 + j;
          int col = ((t < 16) ? 0 : 256) + hc0 + nI;
          w = (k512 < 256) ? wi[(size_t)k512*768 + col] : wh[(size_t)(k512-256)*768 + col];
        } else if (t < 40){
          int k = (t-32)*32 + q*8 + j;
          w = wi[(size_t)k*768 + 512 + hc0 + nI];
        } else {
          int k = (t-40)*32 + q*8 + j;
          w = wh[(size_t)k*768 + 512 + hc0 + nI];
        }
        v[j] = f2bf(w);
      }
      *(short8*)(wlds + (t*64 + lane)*16) = *(short8*)v;
    }
    float br = 0.f, bz = 0.f, bin = 0.f, bhn = 0.f;
    if (wave == 0){
      int cg = hc0 + nI;
      br  = bi[cg] + bh[cg];
      bz  = bi[256+cg] + bh[256+cg];
      bin = bi[512+cg];
      bhn = bh[512+cg];
    }
    floatx4 hst = {0.f,0.f,0.f,0.f};
    __syncthreads();

    for (int s = 0; s < STEPS_; ++s){
      if (tid == 0){
        unsigned int tgt = 16u*(unsigned)(s+1);
        while (__hip_atomic_load(myctr + (set-1), __ATOMIC_RELAXED, __HIP_MEMORY_SCOPE_AGENT) < tgt)
          __builtin_amdgcn_s_sleep(1);
      }
      __syncthreads();
      fence_acq();
      const unsigned short* xs = xBase + ((size_t)(s&1)*4 + g)*4096;
      const unsigned short* hs = hOut  + ((size_t)((s+1)&1)*4 + g)*4096;
      for (int c = tid; c < 1024; c += 256){
        int row = c >> 6, gc = c & 63;
        const unsigned short* src = (gc < 32) ? (xs + row*256 + gc*8) : (hs + row*256 + (gc-32)*8);
        int4 v = *(const int4*)src;
        *(int4*)(stage + (row*64 + (gc ^ (row & 7)))*16) = v;
      }
      __syncthreads();
      floatx4 acc = {0.f,0.f,0.f,0.f};
      if (wave < 2){
        int tb = wave*16;
        #pragma unroll
        for (int kt = 0; kt < 16; ++kt){
          short8 a = *(const short8*)(stage + (nI*64 + ((kt*4+q) ^ (nI & 7)))*16);
          short8 b = *(const short8*)(wlds + ((tb+kt)*64 + lane)*16);
          acc = mfma16(a, b, acc);
        }
      } else if (wave == 2){
        #pragma unroll
        for (int kt = 0; kt < 8; ++kt){
          short8 a = *(const short8*)(stage + (nI*64 + ((kt*4+q) ^ (nI & 7)))*16);
          short8 b = *(const short8*)(wlds + ((32+kt)*64 + lane)*16);
          acc = mfma16(a, b, acc);
        }
      } else {
        #pragma unroll
        for (int kt = 0; kt < 8; ++kt){
          short8 a = *(const short8*)(stage + (nI*64 + ((32 + kt*4+q) ^ (nI & 7)))*16);
          short8 b = *(const short8*)(wlds + ((40+kt)*64 + lane)*16);
          acc = mfma16(a, b, acc);
        }
      }
      __syncthreads();
      float* ex = (float*)stage;
      if (wave >= 1){
        float* dst = ex + (wave-1)*256;
        #pragma unroll
        for (int i = 0; i < 4; ++i) dst[(q*4+i)*16 + nI] = acc[i];
      }
      __syncthreads();
      if (wave == 0){
        unsigned short* ho = hOut + ((size_t)(s&1)*4 + g)*4096;
        #pragma unroll
        for (int i = 0; i < 4; ++i){
          int row = q*4 + i;
          float zr  = ex[0*256 + row*16 + nI];
          float inr = ex[1*256 + row*16 + nI];
          float hnr = ex[2*256 + row*16 + nI];
          float rv = fast_sigm(acc[i] + br);
          float zv = fast_sigm(zr + bz);
          float nv = fast_tanh(inr + bin + rv*(hnr + bhn));
          float hv = (1.f - zv)*nv + zv*hst[i];
          hst[i] = hv;
          ho[row*256 + hc0 + nI] = f2bf(hv);
          if (s == STEPS_-1)
            out[1024000 + gi_*16384 + (size_t)(b0+row)*256 + hc0 + nI] = hv;
        }
      }
      __syncthreads();
      if (tid == 0){
        fence_rel();
        __hip_atomic_fetch_add(myctr + set, 1u, __ATOMIC_RELAXED, __HIP_MEMORY_SCOPE_AGENT);
      }
    }
  }
}

extern "C" void kernel_launch(void* const* d_in, const int* in_sizes, int n_in,
                              void* d_out, int out_size, void* d_ws, size_t ws_size,
                              hipStream_t stream){
  (void)in_sizes; (void)n_in; (void)out_size; (void)ws_size;
  const float* features = (const float*)d_in[0];
  const int*   period   = (const int*)d_in[1];
  const float* rshift   = (const float*)d_in[3];
  const float* pembed   = (const float*)d_in[4];
  const float* fd1_w = (const float*)d_in[5];  const float* fd1_b = (const float*)d_in[6];
  const float* c1w   = (const float*)d_in[7];  const float* c1b   = (const float*)d_in[8];
  const float* c2w   = (const float*)d_in[9];  const float* c2b   = (const float*)d_in[10];
  const float* fd2_w = (const float*)d_in[11]; const float* fd2_b = (const float*)d_in[12];
  const float* sd1_w = (const float*)d_in[13]; const float* sd1_b = (const float*)d_in[14];
  const float* sd2_w = (const float*)d_in[15]; const float* sd2_b = (const float*)d_in[16];
  const float* g1_wi = (const float*)d_in[17]; const float* g1_bi = (const float*)d_in[18];
  const float* g1_wh = (const float*)d_in[19]; const float* g1_bh = (const float*)d_in[20];
  const float* g2_wi = (const float*)d_in[21]; const float* g2_bi = (const float*)d_in[22];
  const float* g2_wh = (const float*)d_in[23]; const float* g2_bh = (const float*)d_in[24];
  const float* g3_wi = (const float*)d_in[25]; const float* g3_bi = (const float*)d_in[26];
  const float* g3_wh = (const float*)d_in[27]; const float* g3_bh = (const float*)d_in[28];
  const float* out_w = (const float*)d_in[29]; const float* out_b = (const float*)d_in[30];

  char* ws = (char*)d_ws;
  size_t off = 0;
  auto alloc = [&](size_t bytes)->char*{
    char* p = ws + off; off += (bytes + 255) & ~(size_t)255; return p;
  };
  unsigned int*  ctr    = (unsigned int*)alloc(64);
  unsigned short* tt2b  = (unsigned short*)alloc(65536);
  unsigned short* h1b   = (unsigned short*)alloc(65536);
  unsigned short* h2b   = (unsigned short*)alloc(65536);
  unsigned short* h3b   = (unsigned short*)alloc(65536);
  float* tt1p = (float*)alloc((size_t)B_*STEPS_*COND_*4);   // 26.2 MB
  float* pr   = (float*)alloc((size_t)B_*STEPS_*SUB_*4);
  float* pi   = (float*)alloc((size_t)B_*STEPS_*SUB_*4);
  float* tbuf = (float*)alloc((size_t)B_*T_*COND_*4);
  float* x1   = (float*)alloc((size_t)B_*102*COND_*4);
  float* x2   = (float*)alloc((size_t)B_*100*COND_*4);
  float* cb   = (float*)alloc((size_t)B_*100*COND_*4);
  float* w1t  = (float*)alloc((size_t)768*256*4);
  float* w2t  = (float*)alloc((size_t)768*256*4);

  k_phase<<<64, 256, 0, stream>>>(period, rshift, pr, pi);
  k_prep<<<256, 256, 0, stream>>>(c1w, c2w, w1t, w2t, ctr, (unsigned int*)tt2b);
  k_gemm<0><<<dim3(104,4), 256, 0, stream>>>(features, pembed, nullptr, period, fd1_w, fd1_b, tbuf);
  k_gemm<1><<<dim3(102,4), 256, 0, stream>>>(tbuf, nullptr, nullptr, nullptr, w1t, c1b, x1);
  k_gemm<2><<<dim3(100,4), 256, 0, stream>>>(x1, nullptr, nullptr, nullptr, w2t, c2b, x2);
  k_gemm<3><<<dim3(100,4), 256, 0, stream>>>(x2, nullptr, nullptr, nullptr, fd2_w, fd2_b, cb);
  k_gemm<4><<<dim3(400,4), 256, 0, stream>>>(cb, pr, pi, nullptr, sd1_w, sd1_b, tt1p);
  k_scan<<<256, 256, 0, stream>>>(sd1_w, sd2_w, sd2_b,
                                  g1_wi, g1_bi, g1_wh, g1_bh,
                                  g2_wi, g2_bi, g2_wh, g2_bh,
                                  g3_wi, g3_bi, g3_wh, g3_bh,
                                  out_w, out_b, tt1p,
                                  tt2b, h1b, h2b, h3b, ctr, (float*)d_out);
}

// Round 3
// 10059.699 us; speedup vs baseline: 1.3186x; 1.3186x over previous
//
#include <hip/hip_runtime.h>
#include <hip/hip_bf16.h>
#include <math.h>

#define B_ 64
#define T_ 104
#define FEAT_ 20
#define PEMB_ 64
#define COND_ 256
#define SUB_ 40
#define NBF_ 100
#define STEPS_ 400

typedef short short8 __attribute__((ext_vector_type(8)));
typedef float floatx4 __attribute__((ext_vector_type(4)));

__device__ inline unsigned short f2bf(float x){
  unsigned int u = __float_as_uint(x);
  unsigned int r = (u + 0x7fffu + ((u >> 16) & 1u)) >> 16;
  return (unsigned short)r;
}
__device__ inline float fast_tanh(float x){
  float e = __expf(2.f*x);
  return 1.f - 2.f*__builtin_amdgcn_rcpf(e + 1.f);
}
__device__ inline float fast_sigm(float x){
  return __builtin_amdgcn_rcpf(1.f + __expf(-x));
}
__device__ inline floatx4 mfma16(short8 a, short8 b, floatx4 c){
  return __builtin_amdgcn_mfma_f32_16x16x32_bf16(a, b, c, 0, 0, 0);
}
// Fine-grained cross-XCD transport: agent-scope accesses hit the coherence
// point (Infinity Cache) directly, no cache-wide fences needed.
__device__ inline unsigned int ld_coh_u32(const unsigned int* p){
  return __hip_atomic_load(p, __ATOMIC_RELAXED, __HIP_MEMORY_SCOPE_AGENT);
}
__device__ inline void st_coh_u32(unsigned int* p, unsigned int v){
  __hip_atomic_store(p, v, __ATOMIC_RELAXED, __HIP_MEMORY_SCOPE_AGENT);
}
__device__ inline void st_coh_u16(unsigned short* p, unsigned short v){
  unsigned int vv = v;
  asm volatile("global_store_short %0, %1, off sc0 sc1" :: "v"(p), "v"(vv) : "memory");
}

// ---------------- phase embedding ----------------
__global__ void k_phase(const int* __restrict__ period, const float* __restrict__ rshift,
                        float* __restrict__ pr, float* __restrict__ pi){
  int b = blockIdx.x;
  __shared__ float cumf[NBF_], w0f[NBF_];
  if (threadIdx.x == 0){
    double acc = 2.0*M_PI*(double)rshift[b];
    for (int f = 0; f < NBF_; ++f){
      double w0 = 2.0*M_PI/(double)period[b*T_ + 3 + f];
      cumf[f] = (float)fmod(acc, 2.0*M_PI);
      w0f[f] = (float)w0;
      acc += 160.0*w0;
    }
  }
  __syncthreads();
  for (int e = threadIdx.x; e < NBF_*160; e += blockDim.x){
    int f = e/160, j = e - f*160;
    float ph = cumf[f] + w0f[f]*(float)j;
    int s = f*4 + j/40, u = j%40;
    pr[((size_t)b*STEPS_ + s)*SUB_ + u] = cosf(ph);
    pi[((size_t)b*STEPS_ + s)*SUB_ + u] = sinf(ph);
  }
}

// ---------------- prep: zero counters/buffers (coherently), transpose conv weights ----------------
__global__ void k_prep(const float* __restrict__ c1w, const float* __restrict__ c2w,
                       float* __restrict__ w1t, float* __restrict__ w2t,
                       unsigned int* __restrict__ ctr, unsigned int* __restrict__ bufs){
  size_t tid = (size_t)blockIdx.x*blockDim.x + threadIdx.x;
  size_t nt = (size_t)gridDim.x*blockDim.x;
  for (size_t e = tid; e < 16; e += nt) st_coh_u32(ctr + e, 0u);
  for (size_t e = tid; e < 65536; e += nt) st_coh_u32(bufs + e, 0u);  // tt2/h1/h2/h3
  for (size_t e = tid; e < 768u*256u; e += nt){
    int kk = (int)(e >> 8), o = (int)(e & 255);
    int i = kk & 255, kc = kk >> 8;
    w1t[e] = c1w[(size_t)o*768 + i*3 + kc];
    w2t[e] = c2w[(size_t)o*768 + i*3 + kc];
  }
}

// ---------------- generic fp32 tiled GEMM (M x K x 256), per-mode A/B gather ----------------
template<int MODE>
__global__ __launch_bounds__(256) void k_gemm(
    const float* __restrict__ a0, const float* __restrict__ a1, const float* __restrict__ a2,
    const int* __restrict__ ip,
    const float* __restrict__ Bm, const float* __restrict__ bias, float* __restrict__ C)
{
  constexpr int KT = (MODE==0) ? 6 : (MODE==1||MODE==2) ? 48 : (MODE==3) ? 16 : 21;
  __shared__ float As[16][68];
  __shared__ float Bs[16][68];
  int tid = threadIdx.x;
  int m0 = blockIdx.x*64, n0 = blockIdx.y*64;
  int tx = tid & 15, ty = tid >> 4;
  float acc[4][4] = {};
  int am = m0 + (tid >> 2);
  int akq = (tid & 3)*4;
  int bk = tid >> 4;
  int bn4 = (tid & 15)*4;

  for (int kt = 0; kt < KT; ++kt){
    int kbase = kt*16;
    float av[4];
    {
      int k0 = kbase + akq;
      if constexpr (MODE==0){
        if (k0 < 20){
          const float* p = a0 + (size_t)am*FEAT_ + k0;
          #pragma unroll
          for (int u=0;u<4;++u) av[u] = p[u];
        } else if (k0 < 84){
          const float* p = a1 + (size_t)ip[am]*PEMB_ + (k0-20);
          #pragma unroll
          for (int u=0;u<4;++u) av[u] = p[u];
        } else { av[0]=av[1]=av[2]=av[3]=0.f; }
      } else if constexpr (MODE==1){
        int b = am/102, t2 = am - b*102;
        int i = k0 & 255, kc = k0 >> 8;
        const float* p = a0 + ((size_t)(b*T_ + t2 + kc))*COND_ + i;
        #pragma unroll
        for (int u=0;u<4;++u) av[u] = p[u];
      } else if constexpr (MODE==2){
        int b = am/100, t2 = am - b*100;
        int i = k0 & 255, kc = k0 >> 8;
        const float* p = a0 + ((size_t)(b*102 + t2 + kc))*COND_ + i;
        #pragma unroll
        for (int u=0;u<4;++u) av[u] = p[u];
      } else if constexpr (MODE==3){
        const float* p = a0 + (size_t)am*COND_ + k0;
        #pragma unroll
        for (int u=0;u<4;++u) av[u] = p[u];
      } else {
        int b = am/400, s = am - b*400;
        const float* p;
        if (k0 < 256)      p = a0 + ((size_t)(b*100 + (s>>2)))*COND_ + k0;
        else if (k0 < 296) p = a1 + ((size_t)(b*400 + s))*SUB_ + (k0-256);
        else               p = a2 + ((size_t)(b*400 + s))*SUB_ + (k0-296);
        #pragma unroll
        for (int u=0;u<4;++u) av[u] = p[u];
      }
    }
    float bv[4];
    {
      int kB = kbase + bk;
      if constexpr (MODE==0){
        if (kB < 84){
          const float* p = Bm + (size_t)kB*256 + n0 + bn4;
          #pragma unroll
          for (int u=0;u<4;++u) bv[u] = p[u];
        } else { bv[0]=bv[1]=bv[2]=bv[3]=0.f; }
      } else if constexpr (MODE==4){
        int krow = (kB < 256) ? kB : kB + 40;
        const float* p = Bm + (size_t)krow*256 + n0 + bn4;
        #pragma unroll
        for (int u=0;u<4;++u) bv[u] = p[u];
      } else {
        const float* p = Bm + (size_t)kB*256 + n0 + bn4;
        #pragma unroll
        for (int u=0;u<4;++u) bv[u] = p[u];
      }
    }
    #pragma unroll
    for (int u=0;u<4;++u) As[akq+u][tid>>2] = av[u];
    #pragma unroll
    for (int u=0;u<4;++u) Bs[bk][bn4+u] = bv[u];
    __syncthreads();
    #pragma unroll
    for (int k = 0; k < 16; ++k){
      float a4[4], b4[4];
      #pragma unroll
      for (int i=0;i<4;++i) a4[i] = As[k][ty*4+i];
      #pragma unroll
      for (int j=0;j<4;++j) b4[j] = Bs[k][tx*4+j];
      #pragma unroll
      for (int i=0;i<4;++i)
        #pragma unroll
        for (int j=0;j<4;++j)
          acc[i][j] += a4[i]*b4[j];
    }
    __syncthreads();
  }
  #pragma unroll
  for (int i=0;i<4;++i){
    int m = m0 + ty*4 + i;
    #pragma unroll
    for (int j=0;j<4;++j){
      int n = n0 + tx*4 + j;
      float v = acc[i][j] + bias[n];
      if constexpr (MODE != 4) v = fast_tanh(v);
      C[(size_t)m*256 + n] = v;
    }
  }
}

// ---------------- persistent AR scan ----------------
// grid 256 = 4 clusters x (16 S1 + 16 G1 + 16 G2 + 16 G3), 256 thr/block, MFMA bf16.
// Cross-block handoff: coherent (sc0 sc1) payload stores/loads at MALL + relaxed
// atomic counters. No cache-wide fences.
__global__ __launch_bounds__(256, 1) void k_scan(
  const float* __restrict__ sd1_w, const float* __restrict__ sd2_w, const float* __restrict__ sd2_b,
  const float* __restrict__ g1_wi, const float* __restrict__ g1_bi, const float* __restrict__ g1_wh, const float* __restrict__ g1_bh,
  const float* __restrict__ g2_wi, const float* __restrict__ g2_bi, const float* __restrict__ g2_wh, const float* __restrict__ g2_bh,
  const float* __restrict__ g3_wi, const float* __restrict__ g3_bi, const float* __restrict__ g3_wh, const float* __restrict__ g3_bh,
  const float* __restrict__ out_w, const float* __restrict__ out_b,
  const float* __restrict__ tt1p,
  unsigned short* __restrict__ tt2buf, unsigned short* __restrict__ h1buf,
  unsigned short* __restrict__ h2buf, unsigned short* __restrict__ h3buf,
  unsigned int* __restrict__ ctr, float* __restrict__ out)
{
  __shared__ __align__(16) char smem[65536];
  int tid = threadIdx.x;
  int lane = tid & 63, wave = tid >> 6;
  int q = lane >> 4, nI = lane & 15;
  int bI = blockIdx.x;
  int g = bI >> 6, rr = bI & 63;
  int set = rr >> 4, sl = rr & 15;
  int b0 = g*16;
  unsigned int* myctr = ctr + g*4;

  if (set == 0){
    // ===== S1: h3 -> prev -> tt1 -> tt2-slice =====
    char* outwF = smem;            // 24576: out_w frags (3 ntiles x 8 ktiles)
    char* sd1p0 = smem + 24576;    // 16384: sd1 prev-rows, K-tile0 (k 0..31)
    char* sd1p1 = smem + 40960;    // 4096:  sd1 prev-rows, K-tile1 (k 32..39, q==0 lanes)
    char* sd2F  = smem + 45056;    // 8192:  sd2 slice frags (8 ktiles)
    char* stage = smem + 53248;    // 8192:  16 rows x 32 swizzled 16B chunks
    char* prevl = smem + 61440;    // 2304:  16 x 72 bf16
    int col1 = sl*16 + nI;

    for (int t = wave; t < 24; t += 4){
      int nt = t >> 3, kk = t & 7;
      int c = nt*16 + nI;
      unsigned short v[8];
      #pragma unroll
      for (int j = 0; j < 8; ++j){
        int k = kk*32 + q*8 + j;
        v[j] = (c < 40) ? f2bf(out_w[(size_t)k*40 + c]) : (unsigned short)0;
      }
      *(short8*)(outwF + (t*64 + lane)*16) = *(short8*)v;
    }
    for (int t = wave; t < 16; t += 4){
      unsigned short v[8];
      #pragma unroll
      for (int j = 0; j < 8; ++j){
        int k = q*8 + j;
        v[j] = f2bf(sd1_w[(size_t)(256+k)*256 + t*16 + nI]);
      }
      *(short8*)(sd1p0 + (t*64 + lane)*16) = *(short8*)v;
    }
    {
      int nt = tid >> 4, ln = tid & 15;
      unsigned short v[8];
      #pragma unroll
      for (int j = 0; j < 8; ++j)
        v[j] = f2bf(sd1_w[(size_t)(256+32+j)*256 + nt*16 + ln]);
      *(short8*)(sd1p1 + tid*16) = *(short8*)v;
    }
    for (int t = wave; t < 8; t += 4){
      unsigned short v[8];
      #pragma unroll
      for (int j = 0; j < 8; ++j){
        int k = t*32 + q*8 + j;
        v[j] = f2bf(sd2_w[(size_t)k*256 + col1]);
      }
      *(short8*)(sd2F + (t*64 + lane)*16) = *(short8*)v;
    }
    for (int e = tid; e < 16*72; e += 256) *(unsigned short*)(prevl + e*2) = 0;
    float bout = 0.f;
    if (wave < 3){ int c = wave*16 + nI; if (c < 40) bout = out_b[c]; }
    float bsd2 = sd2_b[col1];
    __syncthreads();

    for (int s = 0; s <= STEPS_; ++s){
      if (s > 0){
        if (tid == 0){
          unsigned int tgt = 16u*(unsigned)s;
          while (__hip_atomic_load(myctr+3, __ATOMIC_RELAXED, __HIP_MEMORY_SCOPE_AGENT) < tgt)
            __builtin_amdgcn_s_sleep(1);
        }
        __syncthreads();
        const unsigned short* h3s = h3buf + ((size_t)((s+1)&1)*4 + g)*4096;
        for (int c = tid; c < 512; c += 256){
          int row = c >> 5, gc = c & 31;
          const unsigned int* src = (const unsigned int*)(h3s + row*256 + gc*8);
          unsigned int w0 = ld_coh_u32(src+0), w1 = ld_coh_u32(src+1);
          unsigned int w2 = ld_coh_u32(src+2), w3 = ld_coh_u32(src+3);
          unsigned int* dst = (unsigned int*)(stage + (row*32 + (gc ^ (row & 7)))*16);
          dst[0]=w0; dst[1]=w1; dst[2]=w2; dst[3]=w3;
        }
        __syncthreads();
        if (wave < 3){
          floatx4 acc = {0.f,0.f,0.f,0.f};
          #pragma unroll
          for (int kk = 0; kk < 8; ++kk){
            short8 a = *(const short8*)(stage + (nI*32 + ((kk*4+q) ^ (nI & 7)))*16);
            short8 b = *(const short8*)(outwF + ((wave*8+kk)*64 + lane)*16);
            acc = mfma16(a, b, acc);
          }
          int c = wave*16 + nI;
          #pragma unroll
          for (int i = 0; i < 4; ++i){
            int row = q*4 + i;
            float pv = (c < 40) ? fast_tanh(acc[i] + bout) : 0.f;
            *(unsigned short*)(prevl + (row*72 + c)*2) = f2bf(pv);
            if (sl == 0 && c < 40)
              out[(size_t)(b0+row)*16000 + (size_t)(s-1)*40 + c] = pv;
          }
        }
      }
      if (s == STEPS_) break;
      __syncthreads();
      // tt1 = tanh(tt1p[s] + prev @ sd1p) -> stage (full 16x256, replicated)
      #pragma unroll
      for (int ii = 0; ii < 4; ++ii){
        int nt = wave*4 + ii;
        floatx4 acc = {0.f,0.f,0.f,0.f};
        short8 a0v = *(const short8*)(prevl + nI*144 + q*16);
        short8 b0v = *(const short8*)(sd1p0 + (nt*64 + lane)*16);
        acc = mfma16(a0v, b0v, acc);
        short8 a1v = *(const short8*)(prevl + nI*144 + 64 + q*16);
        short8 b1v = {0,0,0,0,0,0,0,0};
        if (q == 0) b1v = *(const short8*)(sd1p1 + (nt*16 + nI)*16);
        acc = mfma16(a1v, b1v, acc);
        int c = nt*16 + nI;
        #pragma unroll
        for (int i = 0; i < 4; ++i){
          int row = q*4 + i;
          float tv = fast_tanh(acc[i] + tt1p[((size_t)(b0+row)*STEPS_ + s)*COND_ + c]);
          int gc = c >> 3;
          *(unsigned short*)(stage + (row*32 + (gc ^ (row & 7)))*16 + (c & 7)*2) = f2bf(tv);
        }
      }
      __syncthreads();
      if (wave == 0){
        floatx4 acc = {0.f,0.f,0.f,0.f};
        #pragma unroll
        for (int kk = 0; kk < 8; ++kk){
          short8 a = *(const short8*)(stage + (nI*32 + ((kk*4+q) ^ (nI & 7)))*16);
          short8 b = *(const short8*)(sd2F + (kk*64 + lane)*16);
          acc = mfma16(a, b, acc);
        }
        unsigned short* t2 = tt2buf + ((size_t)(s&1)*4 + g)*4096;
        #pragma unroll
        for (int i = 0; i < 4; ++i){
          int row = q*4 + i;
          st_coh_u16(&t2[row*256 + col1], f2bf(fast_tanh(acc[i] + bsd2)));
        }
      }
      __syncthreads();   // drains vmcnt of coherent stores (all waves) before flag
      if (tid == 0)
        __hip_atomic_fetch_add(myctr+0, 1u, __ATOMIC_RELAXED, __HIP_MEMORY_SCOPE_AGENT);
    }
  } else {
    // ===== GRU set (set-1 = GRU index) =====
    int gi_ = set - 1;
    const float* wi = (gi_==0) ? g1_wi : (gi_==1) ? g2_wi : g3_wi;
    const float* wh = (gi_==0) ? g1_wh : (gi_==1) ? g2_wh : g3_wh;
    const float* bi = (gi_==0) ? g1_bi : (gi_==1) ? g2_bi : g3_bi;
    const float* bh = (gi_==0) ? g1_bh : (gi_==1) ? g2_bh : g3_bh;
    unsigned short* hOut = (gi_==0) ? h1buf : (gi_==1) ? h2buf : h3buf;
    const unsigned short* xBase = (gi_==0) ? tt2buf : (gi_==1) ? h1buf : h2buf;
    char* wlds  = smem;          // 49152: tiles 0..15 r, 16..31 z, 32..39 i_n, 40..47 h_n
    char* stage = smem + 49152;  // 16384: 16 rows x 64 swizzled 16B chunks ([x|h])
    int hc0 = sl*16;

    for (int t = wave; t < 48; t += 4){
      unsigned short v[8];
      #pragma unroll
      for (int j = 0; j < 8; ++j){
        float w;
        if (t < 32){
          int k512 = (t & 15)*32 + q*8 + j;
          int col = ((t < 16) ? 0 : 256) + hc0 + nI;
          w = (k512 < 256) ? wi[(size_t)k512*768 + col] : wh[(size_t)(k512-256)*768 + col];
        } else if (t < 40){
          int k = (t-32)*32 + q*8 + j;
          w = wi[(size_t)k*768 + 512 + hc0 + nI];
        } else {
          int k = (t-40)*32 + q*8 + j;
          w = wh[(size_t)k*768 + 512 + hc0 + nI];
        }
        v[j] = f2bf(w);
      }
      *(short8*)(wlds + (t*64 + lane)*16) = *(short8*)v;
    }
    float br = 0.f, bz = 0.f, bin = 0.f, bhn = 0.f;
    if (wave == 0){
      int cg = hc0 + nI;
      br  = bi[cg] + bh[cg];
      bz  = bi[256+cg] + bh[256+cg];
      bin = bi[512+cg];
      bhn = bh[512+cg];
    }
    floatx4 hst = {0.f,0.f,0.f,0.f};
    __syncthreads();

    for (int s = 0; s < STEPS_; ++s){
      if (tid == 0){
        unsigned int tgt = 16u*(unsigned)(s+1);
        while (__hip_atomic_load(myctr + (set-1), __ATOMIC_RELAXED, __HIP_MEMORY_SCOPE_AGENT) < tgt)
          __builtin_amdgcn_s_sleep(1);
      }
      __syncthreads();
      const unsigned short* xs = xBase + ((size_t)(s&1)*4 + g)*4096;
      const unsigned short* hs = hOut  + ((size_t)((s+1)&1)*4 + g)*4096;
      for (int c = tid; c < 1024; c += 256){
        int row = c >> 6, gc = c & 63;
        const unsigned short* src = (gc < 32) ? (xs + row*256 + gc*8) : (hs + row*256 + (gc-32)*8);
        const unsigned int* s32 = (const unsigned int*)src;
        unsigned int w0 = ld_coh_u32(s32+0), w1 = ld_coh_u32(s32+1);
        unsigned int w2 = ld_coh_u32(s32+2), w3 = ld_coh_u32(s32+3);
        unsigned int* dst = (unsigned int*)(stage + (row*64 + (gc ^ (row & 7)))*16);
        dst[0]=w0; dst[1]=w1; dst[2]=w2; dst[3]=w3;
      }
      __syncthreads();
      floatx4 acc = {0.f,0.f,0.f,0.f};
      if (wave < 2){
        int tb = wave*16;
        #pragma unroll
        for (int kt = 0; kt < 16; ++kt){
          short8 a = *(const short8*)(stage + (nI*64 + ((kt*4+q) ^ (nI & 7)))*16);
          short8 b = *(const short8*)(wlds + ((tb+kt)*64 + lane)*16);
          acc = mfma16(a, b, acc);
        }
      } else if (wave == 2){
        #pragma unroll
        for (int kt = 0; kt < 8; ++kt){
          short8 a = *(const short8*)(stage + (nI*64 + ((kt*4+q) ^ (nI & 7)))*16);
          short8 b = *(const short8*)(wlds + ((32+kt)*64 + lane)*16);
          acc = mfma16(a, b, acc);
        }
      } else {
        #pragma unroll
        for (int kt = 0; kt < 8; ++kt){
          short8 a = *(const short8*)(stage + (nI*64 + ((32 + kt*4+q) ^ (nI & 7)))*16);
          short8 b = *(const short8*)(wlds + ((40+kt)*64 + lane)*16);
          acc = mfma16(a, b, acc);
        }
      }
      __syncthreads();
      float* ex = (float*)stage;
      if (wave >= 1){
        float* dst = ex + (wave-1)*256;
        #pragma unroll
        for (int i = 0; i < 4; ++i) dst[(q*4+i)*16 + nI] = acc[i];
      }
      __syncthreads();
      if (wave == 0){
        unsigned short* ho = hOut + ((size_t)(s&1)*4 + g)*4096;
        #pragma unroll
        for (int i = 0; i < 4; ++i){
          int row = q*4 + i;
          float zr  = ex[0*256 + row*16 + nI];
          float inr = ex[1*256 + row*16 + nI];
          float hnr = ex[2*256 + row*16 + nI];
          float rv = fast_sigm(acc[i] + br);
          float zv = fast_sigm(zr + bz);
          float nv = fast_tanh(inr + bin + rv*(hnr + bhn));
          float hv = (1.f - zv)*nv + zv*hst[i];
          hst[i] = hv;
          st_coh_u16(&ho[row*256 + hc0 + nI], f2bf(hv));
          if (s == STEPS_-1)
            out[1024000 + gi_*16384 + (size_t)(b0+row)*256 + hc0 + nI] = hv;
        }
      }
      __syncthreads();   // drains vmcnt of coherent stores before flag
      if (tid == 0)
        __hip_atomic_fetch_add(myctr + set, 1u, __ATOMIC_RELAXED, __HIP_MEMORY_SCOPE_AGENT);
    }
  }
}

extern "C" void kernel_launch(void* const* d_in, const int* in_sizes, int n_in,
                              void* d_out, int out_size, void* d_ws, size_t ws_size,
                              hipStream_t stream){
  (void)in_sizes; (void)n_in; (void)out_size; (void)ws_size;
  const float* features = (const float*)d_in[0];
  const int*   period   = (const int*)d_in[1];
  const float* rshift   = (const float*)d_in[3];
  const float* pembed   = (const float*)d_in[4];
  const float* fd1_w = (const float*)d_in[5];  const float* fd1_b = (const float*)d_in[6];
  const float* c1w   = (const float*)d_in[7];  const float* c1b   = (const float*)d_in[8];
  const float* c2w   = (const float*)d_in[9];  const float* c2b   = (const float*)d_in[10];
  const float* fd2_w = (const float*)d_in[11]; const float* fd2_b = (const float*)d_in[12];
  const float* sd1_w = (const float*)d_in[13]; const float* sd1_b = (const float*)d_in[14];
  const float* sd2_w = (const float*)d_in[15]; const float* sd2_b = (const float*)d_in[16];
  const float* g1_wi = (const float*)d_in[17]; const float* g1_bi = (const float*)d_in[18];
  const float* g1_wh = (const float*)d_in[19]; const float* g1_bh = (const float*)d_in[20];
  const float* g2_wi = (const float*)d_in[21]; const float* g2_bi = (const float*)d_in[22];
  const float* g2_wh = (const float*)d_in[23]; const float* g2_bh = (const float*)d_in[24];
  const float* g3_wi = (const float*)d_in[25]; const float* g3_bi = (const float*)d_in[26];
  const float* g3_wh = (const float*)d_in[27]; const float* g3_bh = (const float*)d_in[28];
  const float* out_w = (const float*)d_in[29]; const float* out_b = (const float*)d_in[30];

  char* ws = (char*)d_ws;
  size_t off = 0;
  auto alloc = [&](size_t bytes)->char*{
    char* p = ws + off; off += (bytes + 255) & ~(size_t)255; return p;
  };
  unsigned int*  ctr    = (unsigned int*)alloc(64);
  unsigned short* tt2b  = (unsigned short*)alloc(65536);
  unsigned short* h1b   = (unsigned short*)alloc(65536);
  unsigned short* h2b   = (unsigned short*)alloc(65536);
  unsigned short* h3b   = (unsigned short*)alloc(65536);
  float* tt1p = (float*)alloc((size_t)B_*STEPS_*COND_*4);   // 26.2 MB
  float* pr   = (float*)alloc((size_t)B_*STEPS_*SUB_*4);
  float* pi   = (float*)alloc((size_t)B_*STEPS_*SUB_*4);
  float* tbuf = (float*)alloc((size_t)B_*T_*COND_*4);
  float* x1   = (float*)alloc((size_t)B_*102*COND_*4);
  float* x2   = (float*)alloc((size_t)B_*100*COND_*4);
  float* cb   = (float*)alloc((size_t)B_*100*COND_*4);
  float* w1t  = (float*)alloc((size_t)768*256*4);
  float* w2t  = (float*)alloc((size_t)768*256*4);

  k_phase<<<64, 256, 0, stream>>>(period, rshift, pr, pi);
  k_prep<<<256, 256, 0, stream>>>(c1w, c2w, w1t, w2t, ctr, (unsigned int*)tt2b);
  k_gemm<0><<<dim3(104,4), 256, 0, stream>>>(features, pembed, nullptr, period, fd1_w, fd1_b, tbuf);
  k_gemm<1><<<dim3(102,4), 256, 0, stream>>>(tbuf, nullptr, nullptr, nullptr, w1t, c1b, x1);
  k_gemm<2><<<dim3(100,4), 256, 0, stream>>>(x1, nullptr, nullptr, nullptr, w2t, c2b, x2);
  k_gemm<3><<<dim3(100,4), 256, 0, stream>>>(x2, nullptr, nullptr, nullptr, fd2_w, fd2_b, cb);
  k_gemm<4><<<dim3(400,4), 256, 0, stream>>>(cb, pr, pi, nullptr, sd1_w, sd1_b, tt1p);
  k_scan<<<256, 256, 0, stream>>>(sd1_w, sd2_w, sd2_b,
                                  g1_wi, g1_bi, g1_wh, g1_bh,
                                  g2_wi, g2_bi, g2_wh, g2_bh,
                                  g3_wi, g3_bi, g3_wh, g3_bh,
                                  out_w, out_b, tt1p,
                                  tt2b, h1b, h2b, h3b, ctr, (float*)d_out);
}

// Round 4
// 8427.756 us; speedup vs baseline: 1.5739x; 1.1936x over previous
//
#include <hip/hip_runtime.h>
#include <hip/hip_bf16.h>
#include <math.h>

#define B_ 64
#define T_ 104
#define FEAT_ 20
#define PEMB_ 64
#define COND_ 256
#define SUB_ 40
#define NBF_ 100
#define STEPS_ 400

typedef short short8 __attribute__((ext_vector_type(8)));
typedef float floatx4 __attribute__((ext_vector_type(4)));

__device__ inline unsigned short f2bf(float x){
  unsigned int u = __float_as_uint(x);
  unsigned int r = (u + 0x7fffu + ((u >> 16) & 1u)) >> 16;
  return (unsigned short)r;
}
__device__ inline float fast_tanh(float x){
  float e = __expf(2.f*x);
  return 1.f - 2.f*__builtin_amdgcn_rcpf(e + 1.f);
}
__device__ inline float fast_sigm(float x){
  return __builtin_amdgcn_rcpf(1.f + __expf(-x));
}
__device__ inline floatx4 mfma16(short8 a, short8 b, floatx4 c){
  return __builtin_amdgcn_mfma_f32_16x16x32_bf16(a, b, c, 0, 0, 0);
}
// Fine-grained cross-XCD transport via the coherence point (MALL).
__device__ inline unsigned long long ld_coh_u64(const unsigned long long* p){
  return __hip_atomic_load(p, __ATOMIC_RELAXED, __HIP_MEMORY_SCOPE_AGENT);
}
__device__ inline void st_coh_u32(unsigned int* p, unsigned int v){
  __hip_atomic_store(p, v, __ATOMIC_RELAXED, __HIP_MEMORY_SCOPE_AGENT);
}
__device__ inline void st_coh_u16(unsigned short* p, unsigned short v){
  unsigned int vv = v;
  asm volatile("global_store_short %0, %1, off sc0 sc1" :: "v"(p), "v"(vv) : "memory");
}

// ---------------- phase embedding ----------------
__global__ void k_phase(const int* __restrict__ period, const float* __restrict__ rshift,
                        float* __restrict__ pr, float* __restrict__ pi){
  int b = blockIdx.x;
  __shared__ float cumf[NBF_], w0f[NBF_];
  if (threadIdx.x == 0){
    double acc = 2.0*M_PI*(double)rshift[b];
    for (int f = 0; f < NBF_; ++f){
      double w0 = 2.0*M_PI/(double)period[b*T_ + 3 + f];
      cumf[f] = (float)fmod(acc, 2.0*M_PI);
      w0f[f] = (float)w0;
      acc += 160.0*w0;
    }
  }
  __syncthreads();
  for (int e = threadIdx.x; e < NBF_*160; e += blockDim.x){
    int f = e/160, j = e - f*160;
    float ph = cumf[f] + w0f[f]*(float)j;
    int s = f*4 + j/40, u = j%40;
    pr[((size_t)b*STEPS_ + s)*SUB_ + u] = cosf(ph);
    pi[((size_t)b*STEPS_ + s)*SUB_ + u] = sinf(ph);
  }
}

// ---------------- prep ----------------
__global__ void k_prep(const float* __restrict__ c1w, const float* __restrict__ c2w,
                       float* __restrict__ w1t, float* __restrict__ w2t,
                       unsigned int* __restrict__ ctr, unsigned int* __restrict__ bufs){
  size_t tid = (size_t)blockIdx.x*blockDim.x + threadIdx.x;
  size_t nt = (size_t)gridDim.x*blockDim.x;
  for (size_t e = tid; e < 16; e += nt) st_coh_u32(ctr + e, 0u);
  for (size_t e = tid; e < 65536; e += nt) st_coh_u32(bufs + e, 0u);  // tt2/h1/h2/h3
  for (size_t e = tid; e < 768u*256u; e += nt){
    int kk = (int)(e >> 8), o = (int)(e & 255);
    int i = kk & 255, kc = kk >> 8;
    w1t[e] = c1w[(size_t)o*768 + i*3 + kc];
    w2t[e] = c2w[(size_t)o*768 + i*3 + kc];
  }
}

// ---------------- generic fp32 tiled GEMM (M x K x 256) ----------------
// MODE 4 writes tt1p transposed: [s][b][c] for contiguous per-step slices.
template<int MODE>
__global__ __launch_bounds__(256) void k_gemm(
    const float* __restrict__ a0, const float* __restrict__ a1, const float* __restrict__ a2,
    const int* __restrict__ ip,
    const float* __restrict__ Bm, const float* __restrict__ bias, float* __restrict__ C)
{
  constexpr int KT = (MODE==0) ? 6 : (MODE==1||MODE==2) ? 48 : (MODE==3) ? 16 : 21;
  __shared__ float As[16][68];
  __shared__ float Bs[16][68];
  int tid = threadIdx.x;
  int m0 = blockIdx.x*64, n0 = blockIdx.y*64;
  int tx = tid & 15, ty = tid >> 4;
  float acc[4][4] = {};
  int am = m0 + (tid >> 2);
  int akq = (tid & 3)*4;
  int bk = tid >> 4;
  int bn4 = (tid & 15)*4;

  for (int kt = 0; kt < KT; ++kt){
    int kbase = kt*16;
    float av[4];
    {
      int k0 = kbase + akq;
      if constexpr (MODE==0){
        if (k0 < 20){
          const float* p = a0 + (size_t)am*FEAT_ + k0;
          #pragma unroll
          for (int u=0;u<4;++u) av[u] = p[u];
        } else if (k0 < 84){
          const float* p = a1 + (size_t)ip[am]*PEMB_ + (k0-20);
          #pragma unroll
          for (int u=0;u<4;++u) av[u] = p[u];
        } else { av[0]=av[1]=av[2]=av[3]=0.f; }
      } else if constexpr (MODE==1){
        int b = am/102, t2 = am - b*102;
        int i = k0 & 255, kc = k0 >> 8;
        const float* p = a0 + ((size_t)(b*T_ + t2 + kc))*COND_ + i;
        #pragma unroll
        for (int u=0;u<4;++u) av[u] = p[u];
      } else if constexpr (MODE==2){
        int b = am/100, t2 = am - b*100;
        int i = k0 & 255, kc = k0 >> 8;
        const float* p = a0 + ((size_t)(b*102 + t2 + kc))*COND_ + i;
        #pragma unroll
        for (int u=0;u<4;++u) av[u] = p[u];
      } else if constexpr (MODE==3){
        const float* p = a0 + (size_t)am*COND_ + k0;
        #pragma unroll
        for (int u=0;u<4;++u) av[u] = p[u];
      } else {
        int b = am/400, s = am - b*400;
        const float* p;
        if (k0 < 256)      p = a0 + ((size_t)(b*100 + (s>>2)))*COND_ + k0;
        else if (k0 < 296) p = a1 + ((size_t)(b*400 + s))*SUB_ + (k0-256);
        else               p = a2 + ((size_t)(b*400 + s))*SUB_ + (k0-296);
        #pragma unroll
        for (int u=0;u<4;++u) av[u] = p[u];
      }
    }
    float bv[4];
    {
      int kB = kbase + bk;
      if constexpr (MODE==0){
        if (kB < 84){
          const float* p = Bm + (size_t)kB*256 + n0 + bn4;
          #pragma unroll
          for (int u=0;u<4;++u) bv[u] = p[u];
        } else { bv[0]=bv[1]=bv[2]=bv[3]=0.f; }
      } else if constexpr (MODE==4){
        int krow = (kB < 256) ? kB : kB + 40;
        const float* p = Bm + (size_t)krow*256 + n0 + bn4;
        #pragma unroll
        for (int u=0;u<4;++u) bv[u] = p[u];
      } else {
        const float* p = Bm + (size_t)kB*256 + n0 + bn4;
        #pragma unroll
        for (int u=0;u<4;++u) bv[u] = p[u];
      }
    }
    #pragma unroll
    for (int u=0;u<4;++u) As[akq+u][tid>>2] = av[u];
    #pragma unroll
    for (int u=0;u<4;++u) Bs[bk][bn4+u] = bv[u];
    __syncthreads();
    #pragma unroll
    for (int k = 0; k < 16; ++k){
      float a4[4], b4[4];
      #pragma unroll
      for (int i=0;i<4;++i) a4[i] = As[k][ty*4+i];
      #pragma unroll
      for (int j=0;j<4;++j) b4[j] = Bs[k][tx*4+j];
      #pragma unroll
      for (int i=0;i<4;++i)
        #pragma unroll
        for (int j=0;j<4;++j)
          acc[i][j] += a4[i]*b4[j];
    }
    __syncthreads();
  }
  #pragma unroll
  for (int i=0;i<4;++i){
    int m = m0 + ty*4 + i;
    #pragma unroll
    for (int j=0;j<4;++j){
      int n = n0 + tx*4 + j;
      float v = acc[i][j] + bias[n];
      if constexpr (MODE == 4){
        int b = m/400, s = m - b*400;
        C[((size_t)s*64 + b)*256 + n] = v;     // transposed [s][b][c]
      } else {
        C[(size_t)m*256 + n] = fast_tanh(v);
      }
    }
  }
}

// ---------------- persistent AR scan ----------------
// 4 clusters x (16 S1 + 16 G1 + 16 G2 + 16 G3). Critical-path latencies hidden:
// tt1p prefetched to regs before the S1 poll; GRU h-part (h(s-1) load + h-half
// MFMAs) computed before the x poll.
__global__ __launch_bounds__(256, 1) void k_scan(
  const float* __restrict__ sd1_w, const float* __restrict__ sd2_w, const float* __restrict__ sd2_b,
  const float* __restrict__ g1_wi, const float* __restrict__ g1_bi, const float* __restrict__ g1_wh, const float* __restrict__ g1_bh,
  const float* __restrict__ g2_wi, const float* __restrict__ g2_bi, const float* __restrict__ g2_wh, const float* __restrict__ g2_bh,
  const float* __restrict__ g3_wi, const float* __restrict__ g3_bi, const float* __restrict__ g3_wh, const float* __restrict__ g3_bh,
  const float* __restrict__ out_w, const float* __restrict__ out_b,
  const float* __restrict__ tt1p,
  unsigned short* __restrict__ tt2buf, unsigned short* __restrict__ h1buf,
  unsigned short* __restrict__ h2buf, unsigned short* __restrict__ h3buf,
  unsigned int* __restrict__ ctr, float* __restrict__ out)
{
  __shared__ __align__(16) char smem[65536];
  int tid = threadIdx.x;
  int lane = tid & 63, wave = tid >> 6;
  int q = lane >> 4, nI = lane & 15;
  int bI = blockIdx.x;
  int g = bI >> 6, rr = bI & 63;
  int set = rr >> 4, sl = rr & 15;
  int b0 = g*16;
  unsigned int* myctr = ctr + g*4;

  if (set == 0){
    // ===== S1: h3 -> prev -> tt1 -> tt2-slice =====
    char* outwF = smem;            // 24576
    char* sd1p0 = smem + 24576;    // 16384
    char* sd1p1 = smem + 40960;    // 4096
    char* sd2F  = smem + 45056;    // 8192
    char* stage = smem + 53248;    // 8192
    char* prevl = smem + 61440;    // 2304
    int col1 = sl*16 + nI;

    for (int t = wave; t < 24; t += 4){
      int nt = t >> 3, kk = t & 7;
      int c = nt*16 + nI;
      unsigned short v[8];
      #pragma unroll
      for (int j = 0; j < 8; ++j){
        int k = kk*32 + q*8 + j;
        v[j] = (c < 40) ? f2bf(out_w[(size_t)k*40 + c]) : (unsigned short)0;
      }
      *(short8*)(outwF + (t*64 + lane)*16) = *(short8*)v;
    }
    for (int t = wave; t < 16; t += 4){
      unsigned short v[8];
      #pragma unroll
      for (int j = 0; j < 8; ++j){
        int k = q*8 + j;
        v[j] = f2bf(sd1_w[(size_t)(256+k)*256 + t*16 + nI]);
      }
      *(short8*)(sd1p0 + (t*64 + lane)*16) = *(short8*)v;
    }
    {
      int nt = tid >> 4, ln = tid & 15;
      unsigned short v[8];
      #pragma unroll
      for (int j = 0; j < 8; ++j)
        v[j] = f2bf(sd1_w[(size_t)(256+32+j)*256 + nt*16 + ln]);
      *(short8*)(sd1p1 + tid*16) = *(short8*)v;
    }
    for (int t = wave; t < 8; t += 4){
      unsigned short v[8];
      #pragma unroll
      for (int j = 0; j < 8; ++j){
        int k = t*32 + q*8 + j;
        v[j] = f2bf(sd2_w[(size_t)k*256 + col1]);
      }
      *(short8*)(sd2F + (t*64 + lane)*16) = *(short8*)v;
    }
    for (int e = tid; e < 16*72; e += 256) *(unsigned short*)(prevl + e*2) = 0;
    float bout = 0.f;
    if (wave < 3){ int c = wave*16 + nI; if (c < 40) bout = out_b[c]; }
    float bsd2 = sd2_b[col1];
    __syncthreads();

    for (int s = 0; s <= STEPS_; ++s){
      // prefetch tt1p slice for this step into regs (off the critical path)
      float t1r[16];
      if (s < STEPS_){
        const float* tb = tt1p + ((size_t)s*64 + b0)*256;
        #pragma unroll
        for (int ii = 0; ii < 4; ++ii){
          int c = (wave*4 + ii)*16 + nI;
          #pragma unroll
          for (int i = 0; i < 4; ++i)
            t1r[ii*4+i] = tb[(q*4+i)*256 + c];
        }
      }
      if (s > 0){
        if (tid == 0){
          unsigned int tgt = 16u*(unsigned)s;
          while (__hip_atomic_load(myctr+3, __ATOMIC_RELAXED, __HIP_MEMORY_SCOPE_AGENT) < tgt)
            __builtin_amdgcn_s_sleep(1);
        }
        __syncthreads();
        const unsigned short* h3s = h3buf + ((size_t)((s+1)&1)*4 + g)*4096;
        for (int c = tid; c < 512; c += 256){
          int row = c >> 5, gc = c & 31;
          const unsigned long long* sp = (const unsigned long long*)(h3s + row*256 + gc*8);
          unsigned long long w0 = ld_coh_u64(sp), w1 = ld_coh_u64(sp+1);
          unsigned long long* dst = (unsigned long long*)(stage + (row*32 + (gc ^ (row & 7)))*16);
          dst[0]=w0; dst[1]=w1;
        }
        __syncthreads();
        if (wave < 3){
          floatx4 acc = {0.f,0.f,0.f,0.f};
          #pragma unroll
          for (int kk = 0; kk < 8; ++kk){
            short8 a = *(const short8*)(stage + (nI*32 + ((kk*4+q) ^ (nI & 7)))*16);
            short8 b = *(const short8*)(outwF + ((wave*8+kk)*64 + lane)*16);
            acc = mfma16(a, b, acc);
          }
          int c = wave*16 + nI;
          #pragma unroll
          for (int i = 0; i < 4; ++i){
            int row = q*4 + i;
            float pv = (c < 40) ? fast_tanh(acc[i] + bout) : 0.f;
            *(unsigned short*)(prevl + (row*72 + c)*2) = f2bf(pv);
            if (sl == 0 && c < 40)
              out[(size_t)(b0+row)*16000 + (size_t)(s-1)*40 + c] = pv;
          }
        }
      }
      if (s == STEPS_) break;
      __syncthreads();
      // tt1 = tanh(tt1p[s] + prev @ sd1p) -> stage
      #pragma unroll
      for (int ii = 0; ii < 4; ++ii){
        int nt = wave*4 + ii;
        floatx4 acc = {0.f,0.f,0.f,0.f};
        short8 a0v = *(const short8*)(prevl + nI*144 + q*16);
        short8 b0v = *(const short8*)(sd1p0 + (nt*64 + lane)*16);
        acc = mfma16(a0v, b0v, acc);
        short8 a1v = *(const short8*)(prevl + nI*144 + 64 + q*16);
        short8 b1v = {0,0,0,0,0,0,0,0};
        if (q == 0) b1v = *(const short8*)(sd1p1 + (nt*16 + nI)*16);
        acc = mfma16(a1v, b1v, acc);
        int c = nt*16 + nI;
        #pragma unroll
        for (int i = 0; i < 4; ++i){
          int row = q*4 + i;
          float tv = fast_tanh(acc[i] + t1r[ii*4+i]);
          int gc = c >> 3;
          *(unsigned short*)(stage + (row*32 + (gc ^ (row & 7)))*16 + (c & 7)*2) = f2bf(tv);
        }
      }
      __syncthreads();
      if (wave == 0){
        floatx4 acc = {0.f,0.f,0.f,0.f};
        #pragma unroll
        for (int kk = 0; kk < 8; ++kk){
          short8 a = *(const short8*)(stage + (nI*32 + ((kk*4+q) ^ (nI & 7)))*16);
          short8 b = *(const short8*)(sd2F + (kk*64 + lane)*16);
          acc = mfma16(a, b, acc);
        }
        unsigned short* t2 = tt2buf + ((size_t)(s&1)*4 + g)*4096;
        #pragma unroll
        for (int i = 0; i < 4; ++i){
          int row = q*4 + i;
          st_coh_u16(&t2[row*256 + col1], f2bf(fast_tanh(acc[i] + bsd2)));
        }
      }
      __syncthreads();   // drains coherent stores before flag
      if (tid == 0)
        __hip_atomic_fetch_add(myctr+0, 1u, __ATOMIC_RELAXED, __HIP_MEMORY_SCOPE_AGENT);
    }
  } else {
    // ===== GRU set =====
    int gi_ = set - 1;
    const float* wi = (gi_==0) ? g1_wi : (gi_==1) ? g2_wi : g3_wi;
    const float* wh = (gi_==0) ? g1_wh : (gi_==1) ? g2_wh : g3_wh;
    const float* bi = (gi_==0) ? g1_bi : (gi_==1) ? g2_bi : g3_bi;
    const float* bh = (gi_==0) ? g1_bh : (gi_==1) ? g2_bh : g3_bh;
    unsigned short* hOut = (gi_==0) ? h1buf : (gi_==1) ? h2buf : h3buf;
    const unsigned short* xBase = (gi_==0) ? tt2buf : (gi_==1) ? h1buf : h2buf;
    char* wlds  = smem;          // 49152: tiles 0..15 r, 16..31 z, 32..39 i_n, 40..47 h_n
    char* stage = smem + 49152;  // 16384: 16 rows x 64 chunks ([x | h])
    int hc0 = sl*16;

    for (int t = wave; t < 48; t += 4){
      unsigned short v[8];
      #pragma unroll
      for (int j = 0; j < 8; ++j){
        float w;
        if (t < 32){
          int k512 = (t & 15)*32 + q*8 + j;
          int col = ((t < 16) ? 0 : 256) + hc0 + nI;
          w = (k512 < 256) ? wi[(size_t)k512*768 + col] : wh[(size_t)(k512-256)*768 + col];
        } else if (t < 40){
          int k = (t-32)*32 + q*8 + j;
          w = wi[(size_t)k*768 + 512 + hc0 + nI];
        } else {
          int k = (t-40)*32 + q*8 + j;
          w = wh[(size_t)k*768 + 512 + hc0 + nI];
        }
        v[j] = f2bf(w);
      }
      *(short8*)(wlds + (t*64 + lane)*16) = *(short8*)v;
    }
    float br = 0.f, bz = 0.f, bin = 0.f, bhn = 0.f;
    if (wave == 0){
      int cg = hc0 + nI;
      br  = bi[cg] + bh[cg];
      bz  = bi[256+cg] + bh[256+cg];
      bin = bi[512+cg];
      bhn = bh[512+cg];
    }
    floatx4 hst = {0.f,0.f,0.f,0.f};
    __syncthreads();

    for (int s = 0; s < STEPS_; ++s){
      // --- phase A: own-stage sibling guard, stage h(s-1), h-half MFMAs ---
      if (tid == 0 && s > 0){
        unsigned int tgt = 16u*(unsigned)s;
        while (__hip_atomic_load(myctr + set, __ATOMIC_RELAXED, __HIP_MEMORY_SCOPE_AGENT) < tgt)
          __builtin_amdgcn_s_sleep(1);
      }
      __syncthreads();
      const unsigned short* hs = hOut + ((size_t)((s+1)&1)*4 + g)*4096;
      for (int c = tid; c < 512; c += 256){
        int row = c >> 5, gc = c & 31;
        const unsigned long long* sp = (const unsigned long long*)(hs + row*256 + gc*8);
        unsigned long long w0 = ld_coh_u64(sp), w1 = ld_coh_u64(sp+1);
        unsigned long long* dst = (unsigned long long*)(stage + (row*64 + ((32+gc) ^ (row & 7)))*16);
        dst[0]=w0; dst[1]=w1;
      }
      __syncthreads();
      floatx4 acc = {0.f,0.f,0.f,0.f};
      if (wave < 2){
        int tb = wave*16;
        #pragma unroll
        for (int kt = 8; kt < 16; ++kt){
          short8 a = *(const short8*)(stage + (nI*64 + ((kt*4+q) ^ (nI & 7)))*16);
          short8 b = *(const short8*)(wlds + ((tb+kt)*64 + lane)*16);
          acc = mfma16(a, b, acc);
        }
      } else if (wave == 3){
        #pragma unroll
        for (int kt = 0; kt < 8; ++kt){
          short8 a = *(const short8*)(stage + (nI*64 + ((32 + kt*4+q) ^ (nI & 7)))*16);
          short8 b = *(const short8*)(wlds + ((40+kt)*64 + lane)*16);
          acc = mfma16(a, b, acc);
        }
      }
      // --- phase B: wait for x, stage it, x-half MFMAs ---
      if (tid == 0){
        unsigned int tgt = 16u*(unsigned)(s+1);
        while (__hip_atomic_load(myctr + (set-1), __ATOMIC_RELAXED, __HIP_MEMORY_SCOPE_AGENT) < tgt)
          __builtin_amdgcn_s_sleep(1);
      }
      __syncthreads();
      const unsigned short* xs = xBase + ((size_t)(s&1)*4 + g)*4096;
      for (int c = tid; c < 512; c += 256){
        int row = c >> 5, gc = c & 31;
        const unsigned long long* sp = (const unsigned long long*)(xs + row*256 + gc*8);
        unsigned long long w0 = ld_coh_u64(sp), w1 = ld_coh_u64(sp+1);
        unsigned long long* dst = (unsigned long long*)(stage + (row*64 + (gc ^ (row & 7)))*16);
        dst[0]=w0; dst[1]=w1;
      }
      __syncthreads();
      if (wave < 2){
        int tb = wave*16;
        #pragma unroll
        for (int kt = 0; kt < 8; ++kt){
          short8 a = *(const short8*)(stage + (nI*64 + ((kt*4+q) ^ (nI & 7)))*16);
          short8 b = *(const short8*)(wlds + ((tb+kt)*64 + lane)*16);
          acc = mfma16(a, b, acc);
        }
      } else if (wave == 2){
        #pragma unroll
        for (int kt = 0; kt < 8; ++kt){
          short8 a = *(const short8*)(stage + (nI*64 + ((kt*4+q) ^ (nI & 7)))*16);
          short8 b = *(const short8*)(wlds + ((32+kt)*64 + lane)*16);
          acc = mfma16(a, b, acc);
        }
      }
      __syncthreads();
      float* ex = (float*)stage;
      if (wave >= 1){
        float* dst = ex + (wave-1)*256;
        #pragma unroll
        for (int i = 0; i < 4; ++i) dst[(q*4+i)*16 + nI] = acc[i];
      }
      __syncthreads();
      if (wave == 0){
        unsigned short* ho = hOut + ((size_t)(s&1)*4 + g)*4096;
        #pragma unroll
        for (int i = 0; i < 4; ++i){
          int row = q*4 + i;
          float zr  = ex[0*256 + row*16 + nI];
          float inr = ex[1*256 + row*16 + nI];
          float hnr = ex[2*256 + row*16 + nI];
          float rv = fast_sigm(acc[i] + br);
          float zv = fast_sigm(zr + bz);
          float nv = fast_tanh(inr + bin + rv*(hnr + bhn));
          float hv = (1.f - zv)*nv + zv*hst[i];
          hst[i] = hv;
          st_coh_u16(&ho[row*256 + hc0 + nI], f2bf(hv));
          if (s == STEPS_-1)
            out[1024000 + gi_*16384 + (size_t)(b0+row)*256 + hc0 + nI] = hv;
        }
      }
      __syncthreads();   // drains coherent stores before flag
      if (tid == 0)
        __hip_atomic_fetch_add(myctr + set, 1u, __ATOMIC_RELAXED, __HIP_MEMORY_SCOPE_AGENT);
    }
  }
}

extern "C" void kernel_launch(void* const* d_in, const int* in_sizes, int n_in,
                              void* d_out, int out_size, void* d_ws, size_t ws_size,
                              hipStream_t stream){
  (void)in_sizes; (void)n_in; (void)out_size; (void)ws_size;
  const float* features = (const float*)d_in[0];
  const int*   period   = (const int*)d_in[1];
  const float* rshift   = (const float*)d_in[3];
  const float* pembed   = (const float*)d_in[4];
  const float* fd1_w = (const float*)d_in[5];  const float* fd1_b = (const float*)d_in[6];
  const float* c1w   = (const float*)d_in[7];  const float* c1b   = (const float*)d_in[8];
  const float* c2w   = (const float*)d_in[9];  const float* c2b   = (const float*)d_in[10];
  const float* fd2_w = (const float*)d_in[11]; const float* fd2_b = (const float*)d_in[12];
  const float* sd1_w = (const float*)d_in[13]; const float* sd1_b = (const float*)d_in[14];
  const float* sd2_w = (const float*)d_in[15]; const float* sd2_b = (const float*)d_in[16];
  const float* g1_wi = (const float*)d_in[17]; const float* g1_bi = (const float*)d_in[18];
  const float* g1_wh = (const float*)d_in[19]; const float* g1_bh = (const float*)d_in[20];
  const float* g2_wi = (const float*)d_in[21]; const float* g2_bi = (const float*)d_in[22];
  const float* g2_wh = (const float*)d_in[23]; const float* g2_bh = (const float*)d_in[24];
  const float* g3_wi = (const float*)d_in[25]; const float* g3_bi = (const float*)d_in[26];
  const float* g3_wh = (const float*)d_in[27]; const float* g3_bh = (const float*)d_in[28];
  const float* out_w = (const float*)d_in[29]; const float* out_b = (const float*)d_in[30];

  char* ws = (char*)d_ws;
  size_t off = 0;
  auto alloc = [&](size_t bytes)->char*{
    char* p = ws + off; off += (bytes + 255) & ~(size_t)255; return p;
  };
  unsigned int*  ctr    = (unsigned int*)alloc(64);
  unsigned short* tt2b  = (unsigned short*)alloc(65536);
  unsigned short* h1b   = (unsigned short*)alloc(65536);
  unsigned short* h2b   = (unsigned short*)alloc(65536);
  unsigned short* h3b   = (unsigned short*)alloc(65536);
  float* tt1p = (float*)alloc((size_t)B_*STEPS_*COND_*4);   // [s][b][c]
  float* pr   = (float*)alloc((size_t)B_*STEPS_*SUB_*4);
  float* pi   = (float*)alloc((size_t)B_*STEPS_*SUB_*4);
  float* tbuf = (float*)alloc((size_t)B_*T_*COND_*4);
  float* x1   = (float*)alloc((size_t)B_*102*COND_*4);
  float* x2   = (float*)alloc((size_t)B_*100*COND_*4);
  float* cb   = (float*)alloc((size_t)B_*100*COND_*4);
  float* w1t  = (float*)alloc((size_t)768*256*4);
  float* w2t  = (float*)alloc((size_t)768*256*4);

  k_phase<<<64, 256, 0, stream>>>(period, rshift, pr, pi);
  k_prep<<<256, 256, 0, stream>>>(c1w, c2w, w1t, w2t, ctr, (unsigned int*)tt2b);
  k_gemm<0><<<dim3(104,4), 256, 0, stream>>>(features, pembed, nullptr, period, fd1_w, fd1_b, tbuf);
  k_gemm<1><<<dim3(102,4), 256, 0, stream>>>(tbuf, nullptr, nullptr, nullptr, w1t, c1b, x1);
  k_gemm<2><<<dim3(100,4), 256, 0, stream>>>(x1, nullptr, nullptr, nullptr, w2t, c2b, x2);
  k_gemm<3><<<dim3(100,4), 256, 0, stream>>>(x2, nullptr, nullptr, nullptr, fd2_w, fd2_b, cb);
  k_gemm<4><<<dim3(400,4), 256, 0, stream>>>(cb, pr, pi, nullptr, sd1_w, sd1_b, tt1p);
  k_scan<<<256, 256, 0, stream>>>(sd1_w, sd2_w, sd2_b,
                                  g1_wi, g1_bi, g1_wh, g1_bh,
                                  g2_wi, g2_bi, g2_wh, g2_bh,
                                  g3_wi, g3_bi, g3_wh, g3_bh,
                                  out_w, out_b, tt1p,
                                  tt2b, h1b, h2b, h3b, ctr, (float*)d_out);
}

// Round 5
// 4606.355 us; speedup vs baseline: 2.8796x; 1.8296x over previous
//
#include <hip/hip_runtime.h>
#include <hip/hip_bf16.h>
#include <math.h>

#define B_ 64
#define T_ 104
#define FEAT_ 20
#define PEMB_ 64
#define COND_ 256
#define SUB_ 40
#define NBF_ 100
#define STEPS_ 400

typedef short short8 __attribute__((ext_vector_type(8)));
typedef float floatx4 __attribute__((ext_vector_type(4)));

__device__ inline unsigned short f2bf(float x){
  unsigned int u = __float_as_uint(x);
  unsigned int r = (u + 0x7fffu + ((u >> 16) & 1u)) >> 16;
  return (unsigned short)r;
}
__device__ inline float fast_tanh(float x){
  float e = __expf(2.f*x);
  return 1.f - 2.f*__builtin_amdgcn_rcpf(e + 1.f);
}
__device__ inline float fast_sigm(float x){
  return __builtin_amdgcn_rcpf(1.f + __expf(-x));
}
__device__ inline floatx4 mfma16(short8 a, short8 b, floatx4 c){
  return __builtin_amdgcn_mfma_f32_16x16x32_bf16(a, b, c, 0, 0, 0);
}
// Fine-grained cross-XCD transport via the coherence point (MALL).
__device__ inline unsigned long long ld_coh_u64(const unsigned long long* p){
  return __hip_atomic_load(p, __ATOMIC_RELAXED, __HIP_MEMORY_SCOPE_AGENT);
}
__device__ inline unsigned int ld_coh_u32(const unsigned int* p){
  return __hip_atomic_load(p, __ATOMIC_RELAXED, __HIP_MEMORY_SCOPE_AGENT);
}
__device__ inline void st_coh_u32(unsigned int* p, unsigned int v){
  __hip_atomic_store(p, v, __ATOMIC_RELAXED, __HIP_MEMORY_SCOPE_AGENT);
}
__device__ inline void st_coh_u16(unsigned short* p, unsigned short v){
  unsigned int vv = v;
  asm volatile("global_store_short %0, %1, off sc0 sc1" :: "v"(p), "v"(vv) : "memory");
}

// flags[stage][cluster][block]: one 64B slot each -> no shared lines, no RMW.
#define FLAG_IDX(st, g, sl) ((((st)*4 + (g))*16 + (sl))*16)

// wave0 poll: lanes 0..15 load sibling flags in parallel, min-reduce, spin.
__device__ inline void wave0_wait(const unsigned int* fb, unsigned int tgt,
                                  int wave, int lane){
  if (wave == 0){
    for (;;){
      unsigned int v = 0xFFFFFFFFu;
      if (lane < 16) v = ld_coh_u32(fb + lane*16);
      #pragma unroll
      for (int off = 1; off < 64; off <<= 1)
        v = min(v, (unsigned int)__shfl_xor((int)v, off, 64));
      if (v >= tgt) break;
      __builtin_amdgcn_s_sleep(1);
    }
  }
}

// ---------------- phase embedding ----------------
__global__ void k_phase(const int* __restrict__ period, const float* __restrict__ rshift,
                        float* __restrict__ pr, float* __restrict__ pi){
  int b = blockIdx.x;
  __shared__ float cumf[NBF_], w0f[NBF_];
  if (threadIdx.x == 0){
    double acc = 2.0*M_PI*(double)rshift[b];
    for (int f = 0; f < NBF_; ++f){
      double w0 = 2.0*M_PI/(double)period[b*T_ + 3 + f];
      cumf[f] = (float)fmod(acc, 2.0*M_PI);
      w0f[f] = (float)w0;
      acc += 160.0*w0;
    }
  }
  __syncthreads();
  for (int e = threadIdx.x; e < NBF_*160; e += blockDim.x){
    int f = e/160, j = e - f*160;
    float ph = cumf[f] + w0f[f]*(float)j;
    int s = f*4 + j/40, u = j%40;
    pr[((size_t)b*STEPS_ + s)*SUB_ + u] = cosf(ph);
    pi[((size_t)b*STEPS_ + s)*SUB_ + u] = sinf(ph);
  }
}

// ---------------- prep ----------------
__global__ void k_prep(const float* __restrict__ c1w, const float* __restrict__ c2w,
                       float* __restrict__ w1t, float* __restrict__ w2t,
                       unsigned int* __restrict__ flags, unsigned int* __restrict__ bufs){
  size_t tid = (size_t)blockIdx.x*blockDim.x + threadIdx.x;
  size_t nt = (size_t)gridDim.x*blockDim.x;
  for (size_t e = tid; e < 4096; e += nt) st_coh_u32(flags + e, 0u);
  for (size_t e = tid; e < 65536; e += nt) st_coh_u32(bufs + e, 0u);  // tt2/h1/h2/h3
  for (size_t e = tid; e < 768u*256u; e += nt){
    int kk = (int)(e >> 8), o = (int)(e & 255);
    int i = kk & 255, kc = kk >> 8;
    w1t[e] = c1w[(size_t)o*768 + i*3 + kc];
    w2t[e] = c2w[(size_t)o*768 + i*3 + kc];
  }
}

// ---------------- generic fp32 tiled GEMM (M x K x 256) ----------------
// MODE 4 writes tt1p transposed: [s][b][c] for contiguous per-step slices.
template<int MODE>
__global__ __launch_bounds__(256) void k_gemm(
    const float* __restrict__ a0, const float* __restrict__ a1, const float* __restrict__ a2,
    const int* __restrict__ ip,
    const float* __restrict__ Bm, const float* __restrict__ bias, float* __restrict__ C)
{
  constexpr int KT = (MODE==0) ? 6 : (MODE==1||MODE==2) ? 48 : (MODE==3) ? 16 : 21;
  __shared__ float As[16][68];
  __shared__ float Bs[16][68];
  int tid = threadIdx.x;
  int m0 = blockIdx.x*64, n0 = blockIdx.y*64;
  int tx = tid & 15, ty = tid >> 4;
  float acc[4][4] = {};
  int am = m0 + (tid >> 2);
  int akq = (tid & 3)*4;
  int bk = tid >> 4;
  int bn4 = (tid & 15)*4;

  for (int kt = 0; kt < KT; ++kt){
    int kbase = kt*16;
    float av[4];
    {
      int k0 = kbase + akq;
      if constexpr (MODE==0){
        if (k0 < 20){
          const float* p = a0 + (size_t)am*FEAT_ + k0;
          #pragma unroll
          for (int u=0;u<4;++u) av[u] = p[u];
        } else if (k0 < 84){
          const float* p = a1 + (size_t)ip[am]*PEMB_ + (k0-20);
          #pragma unroll
          for (int u=0;u<4;++u) av[u] = p[u];
        } else { av[0]=av[1]=av[2]=av[3]=0.f; }
      } else if constexpr (MODE==1){
        int b = am/102, t2 = am - b*102;
        int i = k0 & 255, kc = k0 >> 8;
        const float* p = a0 + ((size_t)(b*T_ + t2 + kc))*COND_ + i;
        #pragma unroll
        for (int u=0;u<4;++u) av[u] = p[u];
      } else if constexpr (MODE==2){
        int b = am/100, t2 = am - b*100;
        int i = k0 & 255, kc = k0 >> 8;
        const float* p = a0 + ((size_t)(b*102 + t2 + kc))*COND_ + i;
        #pragma unroll
        for (int u=0;u<4;++u) av[u] = p[u];
      } else if constexpr (MODE==3){
        const float* p = a0 + (size_t)am*COND_ + k0;
        #pragma unroll
        for (int u=0;u<4;++u) av[u] = p[u];
      } else {
        int b = am/400, s = am - b*400;
        const float* p;
        if (k0 < 256)      p = a0 + ((size_t)(b*100 + (s>>2)))*COND_ + k0;
        else if (k0 < 296) p = a1 + ((size_t)(b*400 + s))*SUB_ + (k0-256);
        else               p = a2 + ((size_t)(b*400 + s))*SUB_ + (k0-296);
        #pragma unroll
        for (int u=0;u<4;++u) av[u] = p[u];
      }
    }
    float bv[4];
    {
      int kB = kbase + bk;
      if constexpr (MODE==0){
        if (kB < 84){
          const float* p = Bm + (size_t)kB*256 + n0 + bn4;
          #pragma unroll
          for (int u=0;u<4;++u) bv[u] = p[u];
        } else { bv[0]=bv[1]=bv[2]=bv[3]=0.f; }
      } else if constexpr (MODE==4){
        int krow = (kB < 256) ? kB : kB + 40;
        const float* p = Bm + (size_t)krow*256 + n0 + bn4;
        #pragma unroll
        for (int u=0;u<4;++u) bv[u] = p[u];
      } else {
        const float* p = Bm + (size_t)kB*256 + n0 + bn4;
        #pragma unroll
        for (int u=0;u<4;++u) bv[u] = p[u];
      }
    }
    #pragma unroll
    for (int u=0;u<4;++u) As[akq+u][tid>>2] = av[u];
    #pragma unroll
    for (int u=0;u<4;++u) Bs[bk][bn4+u] = bv[u];
    __syncthreads();
    #pragma unroll
    for (int k = 0; k < 16; ++k){
      float a4[4], b4[4];
      #pragma unroll
      for (int i=0;i<4;++i) a4[i] = As[k][ty*4+i];
      #pragma unroll
      for (int j=0;j<4;++j) b4[j] = Bs[k][tx*4+j];
      #pragma unroll
      for (int i=0;i<4;++i)
        #pragma unroll
        for (int j=0;j<4;++j)
          acc[i][j] += a4[i]*b4[j];
    }
    __syncthreads();
  }
  #pragma unroll
  for (int i=0;i<4;++i){
    int m = m0 + ty*4 + i;
    #pragma unroll
    for (int j=0;j<4;++j){
      int n = n0 + tx*4 + j;
      float v = acc[i][j] + bias[n];
      if constexpr (MODE == 4){
        int b = m/400, s = m - b*400;
        C[((size_t)s*64 + b)*256 + n] = v;     // transposed [s][b][c]
      } else {
        C[(size_t)m*256 + n] = fast_tanh(v);
      }
    }
  }
}

// ---------------- persistent AR scan ----------------
// 4 clusters x (16 S1 + 16 G1 + 16 G2 + 16 G3). Handshake: per-block epoch
// flags (64B slots, coherent stores, parallel 16-lane poll + min-reduce).
__global__ __launch_bounds__(256, 1) void k_scan(
  const float* __restrict__ sd1_w, const float* __restrict__ sd2_w, const float* __restrict__ sd2_b,
  const float* __restrict__ g1_wi, const float* __restrict__ g1_bi, const float* __restrict__ g1_wh, const float* __restrict__ g1_bh,
  const float* __restrict__ g2_wi, const float* __restrict__ g2_bi, const float* __restrict__ g2_wh, const float* __restrict__ g2_bh,
  const float* __restrict__ g3_wi, const float* __restrict__ g3_bi, const float* __restrict__ g3_wh, const float* __restrict__ g3_bh,
  const float* __restrict__ out_w, const float* __restrict__ out_b,
  const float* __restrict__ tt1p,
  unsigned short* __restrict__ tt2buf, unsigned short* __restrict__ h1buf,
  unsigned short* __restrict__ h2buf, unsigned short* __restrict__ h3buf,
  unsigned int* __restrict__ flags, float* __restrict__ out)
{
  __shared__ __align__(16) char smem[65536];
  int tid = threadIdx.x;
  int lane = tid & 63, wave = tid >> 6;
  int q = lane >> 4, nI = lane & 15;
  int bI = blockIdx.x;
  int g = bI >> 6, rr = bI & 63;
  int set = rr >> 4, sl = rr & 15;
  int b0 = g*16;

  if (set == 0){
    // ===== S1: h3 -> prev -> tt1 -> tt2-slice =====
    char* outwF = smem;            // 24576
    char* sd1p0 = smem + 24576;    // 16384
    char* sd1p1 = smem + 40960;    // 4096
    char* sd2F  = smem + 45056;    // 8192
    char* stage = smem + 53248;    // 8192
    char* prevl = smem + 61440;    // 2304
    int col1 = sl*16 + nI;
    const unsigned int* fb3 = flags + FLAG_IDX(3, g, 0);
    unsigned int* myflag = flags + FLAG_IDX(0, g, sl);

    for (int t = wave; t < 24; t += 4){
      int nt = t >> 3, kk = t & 7;
      int c = nt*16 + nI;
      unsigned short v[8];
      #pragma unroll
      for (int j = 0; j < 8; ++j){
        int k = kk*32 + q*8 + j;
        v[j] = (c < 40) ? f2bf(out_w[(size_t)k*40 + c]) : (unsigned short)0;
      }
      *(short8*)(outwF + (t*64 + lane)*16) = *(short8*)v;
    }
    for (int t = wave; t < 16; t += 4){
      unsigned short v[8];
      #pragma unroll
      for (int j = 0; j < 8; ++j){
        int k = q*8 + j;
        v[j] = f2bf(sd1_w[(size_t)(256+k)*256 + t*16 + nI]);
      }
      *(short8*)(sd1p0 + (t*64 + lane)*16) = *(short8*)v;
    }
    {
      int nt = tid >> 4, ln = tid & 15;
      unsigned short v[8];
      #pragma unroll
      for (int j = 0; j < 8; ++j)
        v[j] = f2bf(sd1_w[(size_t)(256+32+j)*256 + nt*16 + ln]);
      *(short8*)(sd1p1 + tid*16) = *(short8*)v;
    }
    for (int t = wave; t < 8; t += 4){
      unsigned short v[8];
      #pragma unroll
      for (int j = 0; j < 8; ++j){
        int k = t*32 + q*8 + j;
        v[j] = f2bf(sd2_w[(size_t)k*256 + col1]);
      }
      *(short8*)(sd2F + (t*64 + lane)*16) = *(short8*)v;
    }
    for (int e = tid; e < 16*72; e += 256) *(unsigned short*)(prevl + e*2) = 0;
    float bout = 0.f;
    if (wave < 3){ int c = wave*16 + nI; if (c < 40) bout = out_b[c]; }
    float bsd2 = sd2_b[col1];
    __syncthreads();

    for (int s = 0; s <= STEPS_; ++s){
      // prefetch tt1p slice for this step into regs (off the critical path)
      float t1r[16];
      if (s < STEPS_){
        const float* tb = tt1p + ((size_t)s*64 + b0)*256;
        #pragma unroll
        for (int ii = 0; ii < 4; ++ii){
          int c = (wave*4 + ii)*16 + nI;
          #pragma unroll
          for (int i = 0; i < 4; ++i)
            t1r[ii*4+i] = tb[(q*4+i)*256 + c];
        }
      }
      if (s > 0){
        wave0_wait(fb3, (unsigned)s, wave, lane);
        __syncthreads();
        const unsigned short* h3s = h3buf + ((size_t)((s+1)&1)*4 + g)*4096;
        for (int c = tid; c < 512; c += 256){
          int row = c >> 5, gc = c & 31;
          const unsigned long long* sp = (const unsigned long long*)(h3s + row*256 + gc*8);
          unsigned long long w0 = ld_coh_u64(sp), w1 = ld_coh_u64(sp+1);
          unsigned long long* dst = (unsigned long long*)(stage + (row*32 + (gc ^ (row & 7)))*16);
          dst[0]=w0; dst[1]=w1;
        }
        __syncthreads();
        if (wave < 3){
          floatx4 acc = {0.f,0.f,0.f,0.f};
          #pragma unroll
          for (int kk = 0; kk < 8; ++kk){
            short8 a = *(const short8*)(stage + (nI*32 + ((kk*4+q) ^ (nI & 7)))*16);
            short8 b = *(const short8*)(outwF + ((wave*8+kk)*64 + lane)*16);
            acc = mfma16(a, b, acc);
          }
          int c = wave*16 + nI;
          #pragma unroll
          for (int i = 0; i < 4; ++i){
            int row = q*4 + i;
            float pv = (c < 40) ? fast_tanh(acc[i] + bout) : 0.f;
            *(unsigned short*)(prevl + (row*72 + c)*2) = f2bf(pv);
            if (sl == 0 && c < 40)
              out[(size_t)(b0+row)*16000 + (size_t)(s-1)*40 + c] = pv;
          }
        }
      }
      if (s == STEPS_) break;
      __syncthreads();
      // tt1 = tanh(tt1p[s] + prev @ sd1p) -> stage
      #pragma unroll
      for (int ii = 0; ii < 4; ++ii){
        int nt = wave*4 + ii;
        floatx4 acc = {0.f,0.f,0.f,0.f};
        short8 a0v = *(const short8*)(prevl + nI*144 + q*16);
        short8 b0v = *(const short8*)(sd1p0 + (nt*64 + lane)*16);
        acc = mfma16(a0v, b0v, acc);
        short8 a1v = *(const short8*)(prevl + nI*144 + 64 + q*16);
        short8 b1v = {0,0,0,0,0,0,0,0};
        if (q == 0) b1v = *(const short8*)(sd1p1 + (nt*16 + nI)*16);
        acc = mfma16(a1v, b1v, acc);
        int c = nt*16 + nI;
        #pragma unroll
        for (int i = 0; i < 4; ++i){
          int row = q*4 + i;
          float tv = fast_tanh(acc[i] + t1r[ii*4+i]);
          int gc = c >> 3;
          *(unsigned short*)(stage + (row*32 + (gc ^ (row & 7)))*16 + (c & 7)*2) = f2bf(tv);
        }
      }
      __syncthreads();
      if (wave == 0){
        floatx4 acc = {0.f,0.f,0.f,0.f};
        #pragma unroll
        for (int kk = 0; kk < 8; ++kk){
          short8 a = *(const short8*)(stage + (nI*32 + ((kk*4+q) ^ (nI & 7)))*16);
          short8 b = *(const short8*)(sd2F + (kk*64 + lane)*16);
          acc = mfma16(a, b, acc);
        }
        unsigned short* t2 = tt2buf + ((size_t)(s&1)*4 + g)*4096;
        #pragma unroll
        for (int i = 0; i < 4; ++i){
          int row = q*4 + i;
          st_coh_u16(&t2[row*256 + col1], f2bf(fast_tanh(acc[i] + bsd2)));
        }
      }
      __syncthreads();   // drains coherent stores before flag
      if (tid == 0) st_coh_u32(myflag, (unsigned)(s+1));
    }
  } else {
    // ===== GRU set =====
    int gi_ = set - 1;
    const float* wi = (gi_==0) ? g1_wi : (gi_==1) ? g2_wi : g3_wi;
    const float* wh = (gi_==0) ? g1_wh : (gi_==1) ? g2_wh : g3_wh;
    const float* bi = (gi_==0) ? g1_bi : (gi_==1) ? g2_bi : g3_bi;
    const float* bh = (gi_==0) ? g1_bh : (gi_==1) ? g2_bh : g3_bh;
    unsigned short* hOut = (gi_==0) ? h1buf : (gi_==1) ? h2buf : h3buf;
    const unsigned short* xBase = (gi_==0) ? tt2buf : (gi_==1) ? h1buf : h2buf;
    char* wlds  = smem;          // 49152: tiles 0..15 r, 16..31 z, 32..39 i_n, 40..47 h_n
    char* stage = smem + 49152;  // 16384: 16 rows x 64 chunks ([x | h])
    int hc0 = sl*16;
    const unsigned int* fbOwn  = flags + FLAG_IDX(set, g, 0);
    const unsigned int* fbPrev = flags + FLAG_IDX(set-1, g, 0);
    unsigned int* myflag = flags + FLAG_IDX(set, g, sl);

    for (int t = wave; t < 48; t += 4){
      unsigned short v[8];
      #pragma unroll
      for (int j = 0; j < 8; ++j){
        float w;
        if (t < 32){
          int k512 = (t & 15)*32 + q*8 + j;
          int col = ((t < 16) ? 0 : 256) + hc0 + nI;
          w = (k512 < 256) ? wi[(size_t)k512*768 + col] : wh[(size_t)(k512-256)*768 + col];
        } else if (t < 40){
          int k = (t-32)*32 + q*8 + j;
          w = wi[(size_t)k*768 + 512 + hc0 + nI];
        } else {
          int k = (t-40)*32 + q*8 + j;
          w = wh[(size_t)k*768 + 512 + hc0 + nI];
        }
        v[j] = f2bf(w);
      }
      *(short8*)(wlds + (t*64 + lane)*16) = *(short8*)v;
    }
    float br = 0.f, bz = 0.f, bin = 0.f, bhn = 0.f;
    if (wave == 0){
      int cg = hc0 + nI;
      br  = bi[cg] + bh[cg];
      bz  = bi[256+cg] + bh[256+cg];
      bin = bi[512+cg];
      bhn = bh[512+cg];
    }
    floatx4 hst = {0.f,0.f,0.f,0.f};
    __syncthreads();

    for (int s = 0; s < STEPS_; ++s){
      // --- phase A: own-stage sibling guard, stage h(s-1), h-half MFMAs ---
      if (s > 0) wave0_wait(fbOwn, (unsigned)s, wave, lane);
      __syncthreads();
      const unsigned short* hs = hOut + ((size_t)((s+1)&1)*4 + g)*4096;
      for (int c = tid; c < 512; c += 256){
        int row = c >> 5, gc = c & 31;
        const unsigned long long* sp = (const unsigned long long*)(hs + row*256 + gc*8);
        unsigned long long w0 = ld_coh_u64(sp), w1 = ld_coh_u64(sp+1);
        unsigned long long* dst = (unsigned long long*)(stage + (row*64 + ((32+gc) ^ (row & 7)))*16);
        dst[0]=w0; dst[1]=w1;
      }
      __syncthreads();
      floatx4 acc = {0.f,0.f,0.f,0.f};
      if (wave < 2){
        int tb = wave*16;
        #pragma unroll
        for (int kt = 8; kt < 16; ++kt){
          short8 a = *(const short8*)(stage + (nI*64 + ((kt*4+q) ^ (nI & 7)))*16);
          short8 b = *(const short8*)(wlds + ((tb+kt)*64 + lane)*16);
          acc = mfma16(a, b, acc);
        }
      } else if (wave == 3){
        #pragma unroll
        for (int kt = 0; kt < 8; ++kt){
          short8 a = *(const short8*)(stage + (nI*64 + ((32 + kt*4+q) ^ (nI & 7)))*16);
          short8 b = *(const short8*)(wlds + ((40+kt)*64 + lane)*16);
          acc = mfma16(a, b, acc);
        }
      }
      // --- phase B: wait for x, stage it, x-half MFMAs ---
      wave0_wait(fbPrev, (unsigned)(s+1), wave, lane);
      __syncthreads();
      const unsigned short* xs = xBase + ((size_t)(s&1)*4 + g)*4096;
      for (int c = tid; c < 512; c += 256){
        int row = c >> 5, gc = c & 31;
        const unsigned long long* sp = (const unsigned long long*)(xs + row*256 + gc*8);
        unsigned long long w0 = ld_coh_u64(sp), w1 = ld_coh_u64(sp+1);
        unsigned long long* dst = (unsigned long long*)(stage + (row*64 + (gc ^ (row & 7)))*16);
        dst[0]=w0; dst[1]=w1;
      }
      __syncthreads();
      if (wave < 2){
        int tb = wave*16;
        #pragma unroll
        for (int kt = 0; kt < 8; ++kt){
          short8 a = *(const short8*)(stage + (nI*64 + ((kt*4+q) ^ (nI & 7)))*16);
          short8 b = *(const short8*)(wlds + ((tb+kt)*64 + lane)*16);
          acc = mfma16(a, b, acc);
        }
      } else if (wave == 2){
        #pragma unroll
        for (int kt = 0; kt < 8; ++kt){
          short8 a = *(const short8*)(stage + (nI*64 + ((kt*4+q) ^ (nI & 7)))*16);
          short8 b = *(const short8*)(wlds + ((32+kt)*64 + lane)*16);
          acc = mfma16(a, b, acc);
        }
      }
      __syncthreads();
      float* ex = (float*)stage;
      if (wave >= 1){
        float* dst = ex + (wave-1)*256;
        #pragma unroll
        for (int i = 0; i < 4; ++i) dst[(q*4+i)*16 + nI] = acc[i];
      }
      __syncthreads();
      if (wave == 0){
        unsigned short* ho = hOut + ((size_t)(s&1)*4 + g)*4096;
        #pragma unroll
        for (int i = 0; i < 4; ++i){
          int row = q*4 + i;
          float zr  = ex[0*256 + row*16 + nI];
          float inr = ex[1*256 + row*16 + nI];
          float hnr = ex[2*256 + row*16 + nI];
          float rv = fast_sigm(acc[i] + br);
          float zv = fast_sigm(zr + bz);
          float nv = fast_tanh(inr + bin + rv*(hnr + bhn));
          float hv = (1.f - zv)*nv + zv*hst[i];
          hst[i] = hv;
          st_coh_u16(&ho[row*256 + hc0 + nI], f2bf(hv));
          if (s == STEPS_-1)
            out[1024000 + gi_*16384 + (size_t)(b0+row)*256 + hc0 + nI] = hv;
        }
      }
      __syncthreads();   // drains coherent stores before flag
      if (tid == 0) st_coh_u32(myflag, (unsigned)(s+1));
    }
  }
}

extern "C" void kernel_launch(void* const* d_in, const int* in_sizes, int n_in,
                              void* d_out, int out_size, void* d_ws, size_t ws_size,
                              hipStream_t stream){
  (void)in_sizes; (void)n_in; (void)out_size; (void)ws_size;
  const float* features = (const float*)d_in[0];
  const int*   period   = (const int*)d_in[1];
  const float* rshift   = (const float*)d_in[3];
  const float* pembed   = (const float*)d_in[4];
  const float* fd1_w = (const float*)d_in[5];  const float* fd1_b = (const float*)d_in[6];
  const float* c1w   = (const float*)d_in[7];  const float* c1b   = (const float*)d_in[8];
  const float* c2w   = (const float*)d_in[9];  const float* c2b   = (const float*)d_in[10];
  const float* fd2_w = (const float*)d_in[11]; const float* fd2_b = (const float*)d_in[12];
  const float* sd1_w = (const float*)d_in[13]; const float* sd1_b = (const float*)d_in[14];
  const float* sd2_w = (const float*)d_in[15]; const float* sd2_b = (const float*)d_in[16];
  const float* g1_wi = (const float*)d_in[17]; const float* g1_bi = (const float*)d_in[18];
  const float* g1_wh = (const float*)d_in[19]; const float* g1_bh = (const float*)d_in[20];
  const float* g2_wi = (const float*)d_in[21]; const float* g2_bi = (const float*)d_in[22];
  const float* g2_wh = (const float*)d_in[23]; const float* g2_bh = (const float*)d_in[24];
  const float* g3_wi = (const float*)d_in[25]; const float* g3_bi = (const float*)d_in[26];
  const float* g3_wh = (const float*)d_in[27]; const float* g3_bh = (const float*)d_in[28];
  const float* out_w = (const float*)d_in[29]; const float* out_b = (const float*)d_in[30];

  char* ws = (char*)d_ws;
  size_t off = 0;
  auto alloc = [&](size_t bytes)->char*{
    char* p = ws + off; off += (bytes + 255) & ~(size_t)255; return p;
  };
  unsigned int*  flags  = (unsigned int*)alloc(16384);
  unsigned short* tt2b  = (unsigned short*)alloc(65536);
  unsigned short* h1b   = (unsigned short*)alloc(65536);
  unsigned short* h2b   = (unsigned short*)alloc(65536);
  unsigned short* h3b   = (unsigned short*)alloc(65536);
  float* tt1p = (float*)alloc((size_t)B_*STEPS_*COND_*4);   // [s][b][c]
  float* pr   = (float*)alloc((size_t)B_*STEPS_*SUB_*4);
  float* pi   = (float*)alloc((size_t)B_*STEPS_*SUB_*4);
  float* tbuf = (float*)alloc((size_t)B_*T_*COND_*4);
  float* x1   = (float*)alloc((size_t)B_*102*COND_*4);
  float* x2   = (float*)alloc((size_t)B_*100*COND_*4);
  float* cb   = (float*)alloc((size_t)B_*100*COND_*4);
  float* w1t  = (float*)alloc((size_t)768*256*4);
  float* w2t  = (float*)alloc((size_t)768*256*4);

  k_phase<<<64, 256, 0, stream>>>(period, rshift, pr, pi);
  k_prep<<<256, 256, 0, stream>>>(c1w, c2w, w1t, w2t, flags, (unsigned int*)tt2b);
  k_gemm<0><<<dim3(104,4), 256, 0, stream>>>(features, pembed, nullptr, period, fd1_w, fd1_b, tbuf);
  k_gemm<1><<<dim3(102,4), 256, 0, stream>>>(tbuf, nullptr, nullptr, nullptr, w1t, c1b, x1);
  k_gemm<2><<<dim3(100,4), 256, 0, stream>>>(x1, nullptr, nullptr, nullptr, w2t, c2b, x2);
  k_gemm<3><<<dim3(100,4), 256, 0, stream>>>(x2, nullptr, nullptr, nullptr, fd2_w, fd2_b, cb);
  k_gemm<4><<<dim3(400,4), 256, 0, stream>>>(cb, pr, pi, nullptr, sd1_w, sd1_b, tt1p);
  k_scan<<<256, 256, 0, stream>>>(sd1_w, sd2_w, sd2_b,
                                  g1_wi, g1_bi, g1_wh, g1_bh,
                                  g2_wi, g2_bi, g2_wh, g2_bh,
                                  g3_wi, g3_bi, g3_wh, g3_bh,
                                  out_w, out_b, tt1p,
                                  tt2b, h1b, h2b, h3b, flags, (float*)d_out);
}